// Round 10
// baseline (1031.825 us; speedup 1.0000x reference)
//
#include <hip/hip_runtime.h>
#include <math.h>

// F=4, T=12, C=512, HID=256, OUT=12
#define NF 48
#define TT 12

typedef __bf16 v8bf __attribute__((ext_vector_type(8)));
typedef float v16f __attribute__((ext_vector_type(16)));

// ---------------- small prep kernels ----------------

__global__ void k_init_deg(float* __restrict__ deg, int n) {
  int i = blockIdx.x * blockDim.x + threadIdx.x;
  if (i < n) deg[i] = 1.0f;
}

__global__ void k_zeroi(int* __restrict__ p, int n) {
  int i = blockIdx.x * blockDim.x + threadIdx.x;
  if (i < n) p[i] = 0;
}

// merged: deg += w  and  cnt += 1  per edge
__global__ void k_edge(const int* __restrict__ dst, const float* __restrict__ w,
                       float* __restrict__ deg, int* __restrict__ cnt, int e) {
  int i = blockIdx.x * blockDim.x + threadIdx.x;
  if (i < e) {
    int d = dst[i];
    atomicAdd(&deg[d], w[i]);
    atomicAdd(&cnt[d], 1);
  }
}

__global__ void k_dinv(const float* __restrict__ deg, float* __restrict__ dinv, int n) {
  int i = blockIdx.x * blockDim.x + threadIdx.x;
  if (i < n) dinv[i] = rsqrtf(fmaxf(deg[i], 1e-12f));
}

// ---------------- hierarchical scan ----------------

__global__ void k_scan1(const int* __restrict__ cnt, int* __restrict__ pscan,
                        int* __restrict__ bsum, int n) {
  __shared__ int s[256];
  int i = blockIdx.x * 256 + threadIdx.x;
  int v = (i < n) ? cnt[i] : 0;
  s[threadIdx.x] = v;
  __syncthreads();
  for (int off = 1; off < 256; off <<= 1) {
    int t = 0;
    if (threadIdx.x >= off) t = s[threadIdx.x - off];
    __syncthreads();
    s[threadIdx.x] += t;
    __syncthreads();
  }
  if (i < n) pscan[i] = s[threadIdx.x] - v;
  if (threadIdx.x == 255) bsum[blockIdx.x] = s[255];
}

__global__ void k_scan2(const int* __restrict__ bsum, int* __restrict__ bpre, int nb) {
  if (threadIdx.x == 0 && blockIdx.x == 0) {
    int run = 0;
    for (int b = 0; b < nb; b++) { bpre[b] = run; run += bsum[b]; }
  }
}

__global__ void k_scan3(const int* __restrict__ pscan, const int* __restrict__ bpre,
                        int* __restrict__ offs, int n, int e) {
  int i = blockIdx.x * blockDim.x + threadIdx.x;
  if (i < n) offs[i] = pscan[i] + bpre[i >> 8];
  if (i == 0) offs[n] = e;
}

__global__ void k_place(const int* __restrict__ src, const int* __restrict__ dst,
                        const float* __restrict__ w, const int* __restrict__ offs,
                        int* __restrict__ fill, int* __restrict__ csrc,
                        float* __restrict__ cw, int e) {
  int i = blockIdx.x * blockDim.x + threadIdx.x;
  if (i >= e) return;
  int d = dst[i];
  int p = offs[d] + atomicAdd(&fill[d], 1);
  csrc[p] = src[i];
  cw[p] = w[i];
}

__global__ void k_gather(const int* __restrict__ offs, const int* __restrict__ csrc,
                         const float* __restrict__ cw, const float* __restrict__ dinv,
                         const float* __restrict__ x, float* __restrict__ Y, int n) {
  int tg = blockIdx.x * blockDim.x + threadIdx.x;
  if (tg >= n * 12) return;
  int i = tg / 12, q = tg % 12;
  float di = dinv[i];
  const float4* x4 = (const float4*)x;
  float4 sv = x4[(size_t)i * 12 + q];
  float ax = di * sv.x, ay = di * sv.y, az = di * sv.z, aw = di * sv.w;
  int e1 = offs[i + 1];
  for (int e = offs[i]; e < e1; e++) {
    int s = csrc[e];
    float wv = cw[e] * dinv[s];
    float4 xv = x4[(size_t)s * 12 + q];
    ax = fmaf(wv, xv.x, ax); ay = fmaf(wv, xv.y, ay);
    az = fmaf(wv, xv.z, az); aw = fmaf(wv, xv.w, aw);
  }
  float4 o = make_float4(di * ax, di * ay, di * az, di * aw);
  ((float4*)Y)[(size_t)i * 12 + q] = o;
}

// ---------------- weight prep: LDS-tiled transpose into swizzled pack ----------------
// pack layout: [n/128][k/32][ row=n%128 ][ chunk(16B)^(row&3) ][ e ]   (verified R7-R9)
__device__ __forceinline__ size_t packIdx128(int n, int k) {
  int row = n & 127;
  int c = (k & 31) >> 3;
  return (size_t)(n >> 7) * (128 * 512) + (size_t)(k >> 5) * (128 * 32) +
         (size_t)row * 32 + (size_t)((c ^ (row & 3)) << 3) + (k & 7);
}

// MODEW 0: zr (Nout=1024, cols n<512 from Wzl bottom, else Wrl bottom)
// MODEW 1: h  (Nout=512, Whl bottom)    MODEW 2: W1 (Nout=256, plain)
template <int MODEW>
__global__ void k_pack(const float* __restrict__ s0, const float* __restrict__ s1,
                       __bf16* __restrict__ WT) {
  __shared__ __bf16 t[64][72];
  int n0 = blockIdx.x * 64, k0 = blockIdx.y * 64;
#pragma unroll
  for (int p = 0; p < 4; p++) {
    int kk = p * 16 + (threadIdx.x >> 4);
    int nn = (threadIdx.x & 15) * 4;
    int n = n0 + nn, k = k0 + kk;
    float4 v;
    if constexpr (MODEW == 2) {
      v = *(const float4*)(s0 + (size_t)k * 256 + n);
    } else {
      const float* src = s0;
      int nc = n;
      if (MODEW == 0 && n >= 512) { src = s1; nc = n - 512; }
      v = *(const float4*)(src + (size_t)(512 + k) * 512 + nc);
    }
    t[kk][nn + 0] = (__bf16)v.x; t[kk][nn + 1] = (__bf16)v.y;
    t[kk][nn + 2] = (__bf16)v.z; t[kk][nn + 3] = (__bf16)v.w;
  }
  __syncthreads();
#pragma unroll
  for (int u = 0; u < 2; u++) {
    int unit = threadIdx.x * 2 + u;
    int nl = unit >> 3, kg = unit & 7;
    v8bf o;
#pragma unroll
    for (int j = 0; j < 8; j++) o[j] = t[kg * 8 + j][nl];
    *(v8bf*)(WT + packIdx128(n0 + nl, k0 + kg * 8)) = o;
  }
}

__global__ void k_build_eff(const float* __restrict__ Wg, const float* __restrict__ Wl,
                            const float* __restrict__ bg, const float* __restrict__ bl,
                            float* __restrict__ Weff, float* __restrict__ beff,
                            int ostride, int ooff) {
  int idx = blockIdx.x * blockDim.x + threadIdx.x;
  if (idx >= 5 * 512) return;
  int r = idx / 512, c = idx % 512;
  float s = 0.f;
  if (r < 4) {
    for (int k = 0; k < 512; k++) s += Wg[r * 512 + k] * Wl[k * 512 + c];
    Weff[r * ostride + ooff + c] = s;
  } else {
    for (int k = 0; k < 512; k++) s += bg[k] * Wl[k * 512 + c];
    beff[ooff + c] = s + bl[c];
  }
}

__global__ void k_softmax_att(const float* __restrict__ att, float* __restrict__ probs) {
  if (blockIdx.x == 0 && threadIdx.x == 0) {
    float m = -1e30f;
    for (int t = 0; t < TT; t++) m = fmaxf(m, att[t]);
    float e[TT], s = 0.f;
    for (int t = 0; t < TT; t++) { e[t] = expf(att[t] - m); s += e[t]; }
    for (int t = 0; t < TT; t++) probs[t] = e[t] / s;
  }
}

// Wy mini-tiles [n/128][row][k<16]: rows 0..3 = Weff, row4 = beff, rest 0.
__global__ void k_wy(const float* __restrict__ Weff, const float* __restrict__ beff,
                     __bf16* __restrict__ out, int Nout) {
  int idx = blockIdx.x * blockDim.x + threadIdx.x;
  if (idx >= Nout * 16) return;
  int n = idx >> 4, k = idx & 15;
  float v = 0.f;
  if (k < 4) v = Weff ? Weff[k * Nout + n] : 0.f;
  else if (k == 4) v = beff[n];
  out[(size_t)(n >> 7) * 2048 + (size_t)(n & 127) * 16 + k] = (__bf16)v;
}

// Ya[t][n][16]: cols 0..3 = Y[n, f, t], col4 = 1, rest 0.
__global__ void k_ya(const float* __restrict__ Y, __bf16* __restrict__ out, int n) {
  int idx = blockIdx.x * blockDim.x + threadIdx.x;
  if (idx >= TT * n * 16) return;
  int t = idx / (n * 16);
  int r = idx % (n * 16);
  int nn = r >> 4, k = r & 15;
  float v = 0.f;
  if (k < 4) v = Y[(size_t)nn * NF + k * TT + t];
  else if (k == 4) v = 1.f;
  out[idx] = (__bf16)v;
}

// ---------------- MFMA GEMM: 128x128 tile, 32x32x16, dbuf LDS, 1 barrier/iter ----------------
// 4 waves 2x2; each wave 64x64 = 2x2 microtiles -> 8 mfma per BK=32 iter.
// Fully unrolled, named staging regs (no scratch). Y@Weff+beff folded as one
// extra K=16 mfma. bf16 outputs staged via LDS for coalesced stores.
template <int MODE>
__global__ __launch_bounds__(256, (MODE == 1) ? 3 : 4) void k_mm(
    const __bf16* __restrict__ Abf, const __bf16* __restrict__ Bp,
    const __bf16* __restrict__ Rbf, const __bf16* __restrict__ Zbf,
    const __bf16* __restrict__ Ay, const __bf16* __restrict__ Wy,
    float* __restrict__ Ofp, __bf16* __restrict__ Obf, __bf16* __restrict__ ObfR,
    int M, int RB) {
  constexpr int CB = (MODE == 0) ? 8 : (MODE == 1) ? 4 : 2;
  constexpr int BUFS = (MODE == 1) ? 12288 : 8192;  // elems per LDS buffer
  __shared__ __bf16 smem[(MODE == 1) ? 24576 : 16384];

  int s = blockIdx.x;
  int grp = 8 * CB;
  int local = s % grp;
  int rowblk = (s / grp) * 8 + (local & 7);
  int colblk = local >> 3;
  if (rowblk >= RB) return;
  const int row0 = rowblk * 128;

  const int tid = threadIdx.x;
  const int lane = tid & 63, w = tid >> 6;
  const int wr = (w >> 1) * 64, wc = (w & 1) * 64;
  const int l31 = lane & 31, lh = lane >> 5;

  // staging: A/R 128x32 -> row ar, two 16B chunks; B pre-swizzled linear copy
  const int ar = tid >> 1, ac2 = (tid & 1) * 2;
  const __bf16* At = Abf + (size_t)(row0 + ar) * 512 + ac2 * 8;
  const __bf16* Rt = Rbf + (size_t)(row0 + ar) * 512 + ac2 * 8;  // MODE1 only
  const __bf16* Bt = Bp + (size_t)colblk * (128 * 512);
  const int aoff0 = ar * 32 + ((ac2 ^ (ar & 3)) << 3);
  const int aoff1 = ar * 32 + (((ac2 + 1) ^ (ar & 3)) << 3);

  v16f acc[2][2];
#pragma unroll
  for (int i = 0; i < 2; i++)
#pragma unroll
    for (int j = 0; j < 2; j++)
#pragma unroll
      for (int q = 0; q < 16; q++) acc[i][j][q] = 0.f;

  uint4 ra0, ra1, rr0, rr1, rb0, rb1;
  rr0 = rr1 = make_uint4(0, 0, 0, 0);

  auto gload = [&](int kt) {
    ra0 = *(const uint4*)(At + kt * 32);
    ra1 = *(const uint4*)(At + kt * 32 + 8);
    if constexpr (MODE == 1) {
      rr0 = *(const uint4*)(Rt + kt * 32);
      rr1 = *(const uint4*)(Rt + kt * 32 + 8);
    }
    rb0 = *(const uint4*)(Bt + (size_t)kt * 4096 + (size_t)tid * 8);
    rb1 = *(const uint4*)(Bt + (size_t)kt * 4096 + 2048 + (size_t)tid * 8);
  };
  auto lstore = [&](int buf) {
    __bf16* base = smem + buf * BUFS;
    *(uint4*)&base[aoff0] = ra0;
    *(uint4*)&base[aoff1] = ra1;
    if constexpr (MODE == 1) {
      *(uint4*)&base[8192 + aoff0] = rr0;
      *(uint4*)&base[8192 + aoff1] = rr1;
    }
    *(uint4*)&base[4096 + (size_t)tid * 8] = rb0;
    *(uint4*)&base[4096 + 2048 + (size_t)tid * 8] = rb1;
  };
  auto compute = [&](int buf) {
    const __bf16* base = smem + buf * BUFS;
#pragma unroll
    for (int ks = 0; ks < 2; ks++) {
      int kc = ks * 2 + lh;
      v8bf af[2];
#pragma unroll
      for (int mi = 0; mi < 2; mi++) {
        int fr = wr + mi * 32 + l31;
        v8bf a = *(const v8bf*)&base[fr * 32 + ((kc ^ (fr & 3)) << 3)];
        if constexpr (MODE == 1) {
          v8bf r = *(const v8bf*)&base[8192 + fr * 32 + ((kc ^ (fr & 3)) << 3)];
#pragma unroll
          for (int q = 0; q < 8; q++) a[q] = (__bf16)((float)a[q] * (float)r[q]);
        }
        af[mi] = a;
      }
#pragma unroll
      for (int ni = 0; ni < 2; ni++) {
        int fc = wc + ni * 32 + l31;
        v8bf b = *(const v8bf*)&base[4096 + fc * 32 + ((kc ^ (fc & 3)) << 3)];
#pragma unroll
        for (int mi = 0; mi < 2; mi++)
          acc[mi][ni] = __builtin_amdgcn_mfma_f32_32x32x16_bf16(af[mi], b, acc[mi][ni], 0, 0, 0);
      }
    }
  };

  gload(0);
  lstore(0);
  gload(1);
  __syncthreads();
#pragma unroll
  for (int kt = 0; kt < 16; kt++) {
    if (kt < 15) lstore((kt + 1) & 1);
    if (kt < 14) gload(kt + 2);
    compute(kt & 1);
    if (kt < 15) __syncthreads();
  }

  // ---- extra K=16 mfma: + Ay(Y_t|1) @ Wy(Weff|beff)   (buf0 regions, no race w/ buf1)
  {
    int row = tid >> 1, half = tid & 1;
    *(uint4*)&smem[row * 16 + half * 8] =
        *(const uint4*)(Ay + (size_t)(row0 + row) * 16 + half * 8);
    *(uint4*)&smem[4096 + row * 16 + half * 8] =
        *(const uint4*)(Wy + (size_t)colblk * 2048 + (size_t)row * 16 + half * 8);
  }
  __syncthreads();
  {
#pragma unroll
    for (int mi = 0; mi < 2; mi++) {
      v8bf a = *(const v8bf*)&smem[(wr + mi * 32 + l31) * 16 + lh * 8];
#pragma unroll
      for (int ni = 0; ni < 2; ni++) {
        v8bf b = *(const v8bf*)&smem[4096 + (wc + ni * 32 + l31) * 16 + lh * 8];
        acc[mi][ni] = __builtin_amdgcn_mfma_f32_32x32x16_bf16(a, b, acc[mi][ni], 0, 0, 0);
      }
    }
  }
  __syncthreads();  // before reusing smem as output stage

  // ---- epilogue. C layout (32x32): col=lane&31, row=(reg&3)+8*(reg>>2)+4*lh
  if constexpr (MODE == 2) {
#pragma unroll
    for (int mi = 0; mi < 2; mi++) {
#pragma unroll
      for (int ni = 0; ni < 2; ni++) {
        int cl = wc + ni * 32 + l31;
#pragma unroll
        for (int reg = 0; reg < 16; reg++) {
          int rg = row0 + wr + mi * 32 + (reg & 3) + ((reg >> 2) << 3) + (lh << 2);
          if (rg >= M) continue;
          Ofp[(size_t)rg * 256 + colblk * 128 + cl] = fmaxf(acc[mi][ni][reg], 0.f);
        }
      }
    }
  } else if constexpr (MODE == 0) {
#pragma unroll
    for (int mi = 0; mi < 2; mi++) {
#pragma unroll
      for (int ni = 0; ni < 2; ni++) {
        int cl = wc + ni * 32 + l31;
#pragma unroll
        for (int reg = 0; reg < 16; reg++) {
          int lr = wr + mi * 32 + (reg & 3) + ((reg >> 2) << 3) + (lh << 2);
          smem[lr * 128 + cl] = (__bf16)(1.f / (1.f + expf(-acc[mi][ni][reg])));
        }
      }
    }
    __syncthreads();
    int row = tid >> 1, seg = (tid & 1) * 64;
    int rg = row0 + row;
    if (rg < M) {
      __bf16* dst = (colblk < 4) ? Obf : ObfR;
      int cof = (colblk & 3) * 128;
#pragma unroll
      for (int q = 0; q < 8; q++) {
        uint4 v = *(const uint4*)&smem[row * 128 + seg + q * 8];
        *(uint4*)(dst + (size_t)rg * 512 + cof + seg + q * 8) = v;
      }
    }
  } else {  // MODE 1: two 64-row passes, fp32 ht via LDS, coalesced z/hold blend
    float* sF = (float*)smem;
#pragma unroll
    for (int h = 0; h < 2; h++) {
      if ((w >> 1) == h) {
#pragma unroll
        for (int mi = 0; mi < 2; mi++) {
#pragma unroll
          for (int ni = 0; ni < 2; ni++) {
            int cl = wc + ni * 32 + l31;
#pragma unroll
            for (int reg = 0; reg < 16; reg++) {
              int lr = mi * 32 + (reg & 3) + ((reg >> 2) << 3) + (lh << 2);
              sF[lr * 128 + cl] = tanhf(acc[mi][ni][reg]);
            }
          }
        }
      }
      __syncthreads();
      int rloc = tid >> 2, seg = (tid & 3) * 32;
      int rg = row0 + h * 64 + rloc;
      if (rg < M) {
        int cg0 = colblk * 128 + seg;
#pragma unroll
        for (int q = 0; q < 4; q++) {
          v8bf z8 = *(const v8bf*)(Zbf + (size_t)rg * 512 + cg0 + q * 8);
          v8bf h8 = *(const v8bf*)(Abf + (size_t)rg * 512 + cg0 + q * 8);
          v8bf o;
#pragma unroll
          for (int j = 0; j < 8; j++) {
            float z = (float)z8[j];
            float ht = sF[rloc * 128 + seg + q * 8 + j];
            o[j] = (__bf16)(z * (float)h8[j] + (1.f - z) * ht);
          }
          *(v8bf*)(Obf + (size_t)rg * 512 + cg0 + q * 8) = o;
        }
      }
      if (h == 0) __syncthreads();
    }
  }
}

// acc[i,c] = sum_t probs[t] * hist[t+1][i,c];  accRelu = bf16(relu(acc))
__global__ void k_acc(const __bf16* __restrict__ hist, const float* __restrict__ probs,
                      float* __restrict__ acc, __bf16* __restrict__ accRelu, int n) {
  int idx = blockIdx.x * blockDim.x + threadIdx.x;
  if (idx >= n * 64) return;
  size_t off = (size_t)idx * 8;
  size_t S = (size_t)n * 512;
  float s[8] = {0, 0, 0, 0, 0, 0, 0, 0};
#pragma unroll
  for (int t = 0; t < TT; t++) {
    float p = probs[t];
    v8bf h = *(const v8bf*)(hist + (size_t)(t + 1) * S + off);
#pragma unroll
    for (int j = 0; j < 8; j++) s[j] = fmaf(p, (float)h[j], s[j]);
  }
  *(float4*)(acc + off) = make_float4(s[0], s[1], s[2], s[3]);
  *(float4*)(acc + off + 4) = make_float4(s[4], s[5], s[6], s[7]);
  v8bf rl;
#pragma unroll
  for (int j = 0; j < 8; j++) rl[j] = (__bf16)fmaxf(s[j], 0.f);
  *(v8bf*)(accRelu + off) = rl;
}

__global__ void k_head2(const float* __restrict__ T1, const float* __restrict__ W2,
                        const float* __restrict__ b2, float* __restrict__ out0, int M) {
  int idx = blockIdx.x * blockDim.x + threadIdx.x;
  if (idx >= M * 12) return;
  int i = idx / 12, c = idx % 12;
  const float* tr = T1 + (size_t)i * 256;
  float s = b2[c];
  for (int k = 0; k < 256; k++) s = fmaf(tr[k], W2[k * 12 + c], s);
  out0[idx] = s;
}

// ---------------- launch ----------------

extern "C" void kernel_launch(void* const* d_in, const int* in_sizes, int n_in,
                              void* d_out, int out_size, void* d_ws, size_t ws_size,
                              hipStream_t stream) {
  const float* x   = (const float*)d_in[0];
  const int*   ei  = (const int*)d_in[1];
  const float* ea  = (const float*)d_in[2];
  const float* att = (const float*)d_in[3];
  const float* Wzg = (const float*)d_in[4];  const float* bzg = (const float*)d_in[5];
  const float* Wzl = (const float*)d_in[6];  const float* bzl = (const float*)d_in[7];
  const float* Wrg = (const float*)d_in[8];  const float* brg = (const float*)d_in[9];
  const float* Wrl = (const float*)d_in[10]; const float* brl = (const float*)d_in[11];
  const float* Whg = (const float*)d_in[12]; const float* bhg = (const float*)d_in[13];
  const float* Whl = (const float*)d_in[14]; const float* bhl = (const float*)d_in[15];
  const float* W1  = (const float*)d_in[16]; const float* b1  = (const float*)d_in[17];
  const float* W2  = (const float*)d_in[18]; const float* b2  = (const float*)d_in[19];

  const int N = in_sizes[0] / NF;
  const int E = in_sizes[1] / 2;
  const int* srcI = ei;
  const int* dstI = ei + E;

  float* out0 = (float*)d_out;                   // [N,12]
  float* accO = (float*)d_out + (size_t)N * 12;  // [N,512] = H_accum (output 1)

  char* wp = (char*)d_ws;
  auto carve = [&](size_t bytes) -> void* {
    void* p = (void*)wp;
    wp += (bytes + 255) & ~(size_t)255;
    return p;
  };
  float*  deg     = (float*)carve((size_t)N * 4);
  float*  dinv    = (float*)carve((size_t)N * 4);
  float*  probs   = (float*)carve(64);
  float*  Y       = (float*)carve((size_t)N * NF * 4);
  __bf16* WzrP    = (__bf16*)carve((size_t)1024 * 512 * 2);
  __bf16* WhP     = (__bf16*)carve((size_t)512 * 512 * 2);
  __bf16* W1P     = (__bf16*)carve((size_t)256 * 512 * 2);
  float*  Wzr_eff = (float*)carve((size_t)4 * 1024 * 4);
  float*  bzr_eff = (float*)carve((size_t)1024 * 4);
  float*  Wh_eff  = (float*)carve((size_t)4 * 512 * 4);
  float*  bh_eff  = (float*)carve((size_t)512 * 4);
  __bf16* hist    = (__bf16*)carve((size_t)(TT + 1) * N * 512 * 2);  // H_0..H_12 bf16
  __bf16* Zbf     = (__bf16*)carve((size_t)N * 512 * 2);
  __bf16* Rbf     = (__bf16*)carve((size_t)N * 512 * 2);
  __bf16* accRelu = (__bf16*)carve((size_t)N * 512 * 2);
  float*  T1      = (float*)carve((size_t)N * 256 * 4);
  __bf16* Ya      = (__bf16*)carve((size_t)TT * N * 16 * 2);
  __bf16* WyZR    = (__bf16*)carve((size_t)1024 * 16 * 2);
  __bf16* WyH     = (__bf16*)carve((size_t)512 * 16 * 2);
  __bf16* Wy1     = (__bf16*)carve((size_t)256 * 16 * 2);
  int*    cnt     = (int*)carve((size_t)2 * N * 4);  // cnt[N] + fill[N] contiguous
  int*    fill    = cnt + N;
  int*    offs    = (int*)carve((size_t)(N + 1) * 4);
  int*    pscan   = (int*)carve((size_t)N * 4);
  int*    bsum    = (int*)carve(256);
  int*    bpre    = (int*)carve(256);
  int*    csrc    = (int*)carve((size_t)E * 4);
  float*  cw      = (float*)carve((size_t)E * 4);
  (void)carve(512 * 1024);  // tail pad: OOB tile reads stay inside ws
  (void)ws_size; (void)n_in; (void)out_size;

  const int TPB = 256;
  auto cdiv = [](int a, int b) { return (a + b - 1) / b; };
  const size_t S = (size_t)N * 512;

  // degree + CSR counts in one edge pass
  k_init_deg<<<cdiv(N, TPB), TPB, 0, stream>>>(deg, N);
  k_zeroi<<<cdiv(2 * N, TPB), TPB, 0, stream>>>(cnt, 2 * N);
  k_edge<<<cdiv(E, TPB), TPB, 0, stream>>>(dstI, ea, deg, cnt, E);
  k_dinv<<<cdiv(N, TPB), TPB, 0, stream>>>(deg, dinv, N);

  // hierarchical scan -> offs
  const int nb = cdiv(N, 256);
  k_scan1<<<nb, 256, 0, stream>>>(cnt, pscan, bsum, N);
  k_scan2<<<1, 64, 0, stream>>>(bsum, bpre, nb);
  k_scan3<<<cdiv(N, TPB), TPB, 0, stream>>>(pscan, bpre, offs, N, E);
  k_place<<<cdiv(E, TPB), TPB, 0, stream>>>(srcI, dstI, ea, offs, fill, csrc, cw, E);
  k_gather<<<cdiv(N * 12, TPB), TPB, 0, stream>>>(offs, csrc, cw, dinv, x, Y, N);

  // weight prep (LDS-tiled coalesced transposes into swizzled pack)
  {
    dim3 gzr(16, 8); k_pack<0><<<gzr, 256, 0, stream>>>(Wzl, Wrl, WzrP);
    dim3 gh(8, 8);   k_pack<1><<<gh, 256, 0, stream>>>(Whl, nullptr, WhP);
    dim3 g1(4, 8);   k_pack<2><<<g1, 256, 0, stream>>>(W1, nullptr, W1P);
  }
  k_build_eff<<<cdiv(5 * 512, TPB), TPB, 0, stream>>>(Wzg, Wzl, bzg, bzl, Wzr_eff, bzr_eff, 1024, 0);
  k_build_eff<<<cdiv(5 * 512, TPB), TPB, 0, stream>>>(Wrg, Wrl, brg, brl, Wzr_eff, bzr_eff, 1024, 512);
  k_build_eff<<<cdiv(5 * 512, TPB), TPB, 0, stream>>>(Whg, Whl, bhg, bhl, Wh_eff, bh_eff, 512, 0);
  k_softmax_att<<<1, 64, 0, stream>>>(att, probs);
  k_wy<<<cdiv(1024 * 16, TPB), TPB, 0, stream>>>(Wzr_eff, bzr_eff, WyZR, 1024);
  k_wy<<<cdiv(512 * 16, TPB), TPB, 0, stream>>>(Wh_eff, bh_eff, WyH, 512);
  k_wy<<<cdiv(256 * 16, TPB), TPB, 0, stream>>>(nullptr, b1, Wy1, 256);
  k_ya<<<cdiv(TT * N * 16, TPB), TPB, 0, stream>>>(Y, Ya, N);

  // hist slot 0 = H_0 = 0
  k_zeroi<<<cdiv(N * 256, TPB), TPB, 0, stream>>>((int*)hist, N * 256);

  const int RB = cdiv(N, 128);         // 79 row blocks
  const int nGrp = cdiv(RB, 8);        // 10 groups
  for (int t = 0; t < TT; t++) {
    const __bf16* Hbt = hist + (size_t)t * S;
    __bf16* Hbn = hist + (size_t)(t + 1) * S;
    const __bf16* Yat = Ya + (size_t)t * N * 16;
    k_mm<0><<<64 * nGrp, 256, 0, stream>>>(Hbt, WzrP, nullptr, nullptr, Yat, WyZR,
                                           nullptr, Zbf, Rbf, N, RB);
    k_mm<1><<<32 * nGrp, 256, 0, stream>>>(Hbt, WhP, Rbf, Zbf, Yat, WyH,
                                           nullptr, Hbn, nullptr, N, RB);
  }

  // H_accum = sum_t p_t H_{t+1}; head
  k_acc<<<cdiv(N * 64, TPB), TPB, 0, stream>>>(hist, probs, accO, accRelu, N);
  k_mm<2><<<16 * nGrp, 256, 0, stream>>>(accRelu, W1P, nullptr, nullptr, Ya, Wy1,
                                         T1, nullptr, nullptr, N, RB);
  k_head2<<<cdiv(N * 12, TPB), TPB, 0, stream>>>(T1, W2, b2, out0, N);
}

// Round 11
// 842.398 us; speedup vs baseline: 1.2249x; 1.2249x over previous
//
#include <hip/hip_runtime.h>
#include <math.h>

// F=4, T=12, C=512, HID=256, OUT=12
#define NF 48
#define TT 12

typedef __bf16 v8bf __attribute__((ext_vector_type(8)));
typedef float v16f __attribute__((ext_vector_type(16)));

// ---------------- small prep kernels ----------------

// deg=1, cnt=0, fill=0 in one pass
__global__ void k_init(float* __restrict__ deg, int* __restrict__ cnt, int n) {
  int i = blockIdx.x * blockDim.x + threadIdx.x;
  if (i < n) { deg[i] = 1.0f; cnt[i] = 0; cnt[n + i] = 0; }
}

__global__ void k_zeroi(int* __restrict__ p, int n) {
  int i = blockIdx.x * blockDim.x + threadIdx.x;
  if (i < n) p[i] = 0;
}

// merged: deg += w  and  cnt += 1  per edge
__global__ void k_edge(const int* __restrict__ dst, const float* __restrict__ w,
                       float* __restrict__ deg, int* __restrict__ cnt, int e) {
  int i = blockIdx.x * blockDim.x + threadIdx.x;
  if (i < e) {
    int d = dst[i];
    atomicAdd(&deg[d], w[i]);
    atomicAdd(&cnt[d], 1);
  }
}

__global__ void k_dinv(const float* __restrict__ deg, float* __restrict__ dinv, int n) {
  int i = blockIdx.x * blockDim.x + threadIdx.x;
  if (i < n) dinv[i] = rsqrtf(fmaxf(deg[i], 1e-12f));
}

// ---------------- hierarchical scan ----------------

__global__ void k_scan1(const int* __restrict__ cnt, int* __restrict__ pscan,
                        int* __restrict__ bsum, int n) {
  __shared__ int s[256];
  int i = blockIdx.x * 256 + threadIdx.x;
  int v = (i < n) ? cnt[i] : 0;
  s[threadIdx.x] = v;
  __syncthreads();
  for (int off = 1; off < 256; off <<= 1) {
    int t = 0;
    if (threadIdx.x >= off) t = s[threadIdx.x - off];
    __syncthreads();
    s[threadIdx.x] += t;
    __syncthreads();
  }
  if (i < n) pscan[i] = s[threadIdx.x] - v;
  if (threadIdx.x == 255) bsum[blockIdx.x] = s[255];
}

__global__ void k_scan2(const int* __restrict__ bsum, int* __restrict__ bpre, int nb) {
  if (threadIdx.x == 0 && blockIdx.x == 0) {
    int run = 0;
    for (int b = 0; b < nb; b++) { bpre[b] = run; run += bsum[b]; }
  }
}

__global__ void k_scan3(const int* __restrict__ pscan, const int* __restrict__ bpre,
                        int* __restrict__ offs, int n, int e) {
  int i = blockIdx.x * blockDim.x + threadIdx.x;
  if (i < n) offs[i] = pscan[i] + bpre[i >> 8];
  if (i == 0) offs[n] = e;
}

__global__ void k_place(const int* __restrict__ src, const int* __restrict__ dst,
                        const float* __restrict__ w, const int* __restrict__ offs,
                        int* __restrict__ fill, int* __restrict__ csrc,
                        float* __restrict__ cw, int e) {
  int i = blockIdx.x * blockDim.x + threadIdx.x;
  if (i >= e) return;
  int d = dst[i];
  int p = offs[d] + atomicAdd(&fill[d], 1);
  csrc[p] = src[i];
  cw[p] = w[i];
}

__global__ void k_gather(const int* __restrict__ offs, const int* __restrict__ csrc,
                         const float* __restrict__ cw, const float* __restrict__ dinv,
                         const float* __restrict__ x, float* __restrict__ Y, int n) {
  int tg = blockIdx.x * blockDim.x + threadIdx.x;
  if (tg >= n * 12) return;
  int i = tg / 12, q = tg % 12;
  float di = dinv[i];
  const float4* x4 = (const float4*)x;
  float4 sv = x4[(size_t)i * 12 + q];
  float ax = di * sv.x, ay = di * sv.y, az = di * sv.z, aw = di * sv.w;
  int e1 = offs[i + 1];
  for (int e = offs[i]; e < e1; e++) {
    int s = csrc[e];
    float wv = cw[e] * dinv[s];
    float4 xv = x4[(size_t)s * 12 + q];
    ax = fmaf(wv, xv.x, ax); ay = fmaf(wv, xv.y, ay);
    az = fmaf(wv, xv.z, az); aw = fmaf(wv, xv.w, aw);
  }
  float4 o = make_float4(di * ax, di * ay, di * az, di * aw);
  ((float4*)Y)[(size_t)i * 12 + q] = o;
}

// ---------------- weight prep: LDS-tiled transpose into swizzled pack ----------------
// pack layout: [n/128][k/32][ row=n%128 ][ chunk(16B)^(row&3) ][ e ]   (verified R7-R10)
__device__ __forceinline__ size_t packIdx128(int n, int k) {
  int row = n & 127;
  int c = (k & 31) >> 3;
  return (size_t)(n >> 7) * (128 * 512) + (size_t)(k >> 5) * (128 * 32) +
         (size_t)row * 32 + (size_t)((c ^ (row & 3)) << 3) + (k & 7);
}

// MODEW 0: zr (Nout=1024, cols n<512 from Wzl bottom, else Wrl bottom)
// MODEW 1: h  (Nout=512, Whl bottom)    MODEW 2: W1 (Nout=256, plain)
template <int MODEW>
__global__ void k_pack(const float* __restrict__ s0, const float* __restrict__ s1,
                       __bf16* __restrict__ WT) {
  __shared__ __bf16 t[64][72];
  int n0 = blockIdx.x * 64, k0 = blockIdx.y * 64;
#pragma unroll
  for (int p = 0; p < 4; p++) {
    int kk = p * 16 + (threadIdx.x >> 4);
    int nn = (threadIdx.x & 15) * 4;
    int n = n0 + nn, k = k0 + kk;
    float4 v;
    if constexpr (MODEW == 2) {
      v = *(const float4*)(s0 + (size_t)k * 256 + n);
    } else {
      const float* src = s0;
      int nc = n;
      if (MODEW == 0 && n >= 512) { src = s1; nc = n - 512; }
      v = *(const float4*)(src + (size_t)(512 + k) * 512 + nc);
    }
    t[kk][nn + 0] = (__bf16)v.x; t[kk][nn + 1] = (__bf16)v.y;
    t[kk][nn + 2] = (__bf16)v.z; t[kk][nn + 3] = (__bf16)v.w;
  }
  __syncthreads();
#pragma unroll
  for (int u = 0; u < 2; u++) {
    int unit = threadIdx.x * 2 + u;
    int nl = unit >> 3, kg = unit & 7;
    v8bf o;
#pragma unroll
    for (int j = 0; j < 8; j++) o[j] = t[kg * 8 + j][nl];
    *(v8bf*)(WT + packIdx128(n0 + nl, k0 + kg * 8)) = o;
  }
}

// all three gate folds in one launch: seg 0: z (->Wzr_eff@0), 1: r (@512), 2: h
__global__ void k_build_eff3(const float* __restrict__ Wzg, const float* __restrict__ Wzl,
                             const float* __restrict__ bzg, const float* __restrict__ bzl,
                             const float* __restrict__ Wrg, const float* __restrict__ Wrl,
                             const float* __restrict__ brg, const float* __restrict__ brl,
                             const float* __restrict__ Whg, const float* __restrict__ Whl,
                             const float* __restrict__ bhg, const float* __restrict__ bhl,
                             float* __restrict__ WzrE, float* __restrict__ bzrE,
                             float* __restrict__ WhE, float* __restrict__ bhE) {
  int idx = blockIdx.x * blockDim.x + threadIdx.x;
  if (idx >= 3 * 5 * 512) return;
  int seg = idx / 2560;
  int r = (idx % 2560) / 512, c = idx % 512;
  const float *Wg, *Wl, *bg, *bl;
  float *We, *be;
  int ostride, ooff;
  if (seg == 0) { Wg = Wzg; Wl = Wzl; bg = bzg; bl = bzl; We = WzrE; be = bzrE; ostride = 1024; ooff = 0; }
  else if (seg == 1) { Wg = Wrg; Wl = Wrl; bg = brg; bl = brl; We = WzrE; be = bzrE; ostride = 1024; ooff = 512; }
  else { Wg = Whg; Wl = Whl; bg = bhg; bl = bhl; We = WhE; be = bhE; ostride = 512; ooff = 0; }
  float s = 0.f;
  if (r < 4) {
    for (int k = 0; k < 512; k++) s += Wg[r * 512 + k] * Wl[k * 512 + c];
    We[r * ostride + ooff + c] = s;
  } else {
    for (int k = 0; k < 512; k++) s += bg[k] * Wl[k * 512 + c];
    be[ooff + c] = s + bl[c];
  }
}

__global__ void k_softmax_att(const float* __restrict__ att, float* __restrict__ probs) {
  if (blockIdx.x == 0 && threadIdx.x == 0) {
    float m = -1e30f;
    for (int t = 0; t < TT; t++) m = fmaxf(m, att[t]);
    float e[TT], s = 0.f;
    for (int t = 0; t < TT; t++) { e[t] = expf(att[t] - m); s += e[t]; }
    for (int t = 0; t < TT; t++) probs[t] = e[t] / s;
  }
}

// Wy mini-tiles [n/128][row][k<16]: rows 0..3 = Weff, row4 = beff, rest 0.
// One launch for all three (zr 1024 | h 512 | 1 256).
__global__ void k_wy3(const float* __restrict__ WzrE, const float* __restrict__ bzrE,
                      const float* __restrict__ WhE, const float* __restrict__ bhE,
                      const float* __restrict__ b1,
                      __bf16* __restrict__ WyZR, __bf16* __restrict__ WyH,
                      __bf16* __restrict__ Wy1) {
  int idx = blockIdx.x * blockDim.x + threadIdx.x;
  const float* Weff; const float* beff; __bf16* out; int Nout, loc;
  if (idx < 1024 * 16) { Weff = WzrE; beff = bzrE; out = WyZR; Nout = 1024; loc = idx; }
  else if (idx < (1024 + 512) * 16) { Weff = WhE; beff = bhE; out = WyH; Nout = 512; loc = idx - 1024 * 16; }
  else if (idx < (1024 + 512 + 256) * 16) { Weff = nullptr; beff = b1; out = Wy1; Nout = 256; loc = idx - (1024 + 512) * 16; }
  else return;
  int n = loc >> 4, k = loc & 15;
  float v = 0.f;
  if (k < 4) v = Weff ? Weff[k * Nout + n] : 0.f;
  else if (k == 4) v = beff[n];
  out[(size_t)(n >> 7) * 2048 + (size_t)(n & 127) * 16 + k] = (__bf16)v;
}

// Ya[t][n][16]: cols 0..3 = Y[n, f, t], col4 = 1, rest 0.
__global__ void k_ya(const float* __restrict__ Y, __bf16* __restrict__ out, int n) {
  int idx = blockIdx.x * blockDim.x + threadIdx.x;
  if (idx >= TT * n * 16) return;
  int t = idx / (n * 16);
  int r = idx % (n * 16);
  int nn = r >> 4, k = r & 15;
  float v = 0.f;
  if (k < 4) v = Y[(size_t)nn * NF + k * TT + t];
  else if (k == 4) v = 1.f;
  out[idx] = (__bf16)v;
}

// t=0 shortcut: H0=0 => z=sigmoid(Yz), ht=tanh(Yh), H1=(1-z)*ht, elementwise (fp32)
__global__ void k_t0(const float* __restrict__ Y,
                     const float* __restrict__ WzrE, const float* __restrict__ bzrE,
                     const float* __restrict__ WhE, const float* __restrict__ bhE,
                     __bf16* __restrict__ H1, int n) {
  int idx = blockIdx.x * blockDim.x + threadIdx.x;
  if (idx >= n * 512) return;
  int i = idx >> 9, c = idx & 511;
  float y0 = Y[(size_t)i * NF + 0], y1 = Y[(size_t)i * NF + 12];
  float y2 = Y[(size_t)i * NF + 24], y3 = Y[(size_t)i * NF + 36];
  float pz = bzrE[c] + y0 * WzrE[c] + y1 * WzrE[1024 + c] +
             y2 * WzrE[2048 + c] + y3 * WzrE[3072 + c];
  float ph = bhE[c] + y0 * WhE[c] + y1 * WhE[512 + c] +
             y2 * WhE[1024 + c] + y3 * WhE[1536 + c];
  float z = 1.f / (1.f + expf(-pz));
  H1[idx] = (__bf16)((1.f - z) * tanhf(ph));
}

// ---------------- MFMA GEMM: 64x128 tile, 32x32x16, dbuf LDS, 1 barrier/iter ----------------
// (R9 core, proven 966us; launch_bounds bumped to 6 blocks/CU for MODE0/2)
template <int MODE>
__global__ __launch_bounds__(256, (MODE == 1) ? 4 : 6) void k_mm(
    const __bf16* __restrict__ Abf, const __bf16* __restrict__ Bp,
    const __bf16* __restrict__ Rbf, const __bf16* __restrict__ Zbf,
    const __bf16* __restrict__ Ay, const __bf16* __restrict__ Wy,
    float* __restrict__ Ofp, __bf16* __restrict__ Obf, __bf16* __restrict__ ObfR,
    int M, int RB) {
  constexpr int CB = (MODE == 0) ? 8 : (MODE == 1) ? 4 : 2;
  constexpr int BUFS = (MODE == 1) ? 8192 : 6144;  // elems per LDS buffer
  __shared__ __bf16 smem[(MODE == 1) ? 16384 : 12288];

  int s = blockIdx.x;
  int grp = 8 * CB;
  int local = s % grp;
  int rowblk = (s / grp) * 8 + (local & 7);
  int colblk = local >> 3;
  if (rowblk >= RB) return;
  const int row0 = rowblk * 64;

  const int tid = threadIdx.x;
  const int lane = tid & 63, w = tid >> 6;
  const int wr = (w >> 1) * 32, wc = (w & 1) * 64;
  const int l31 = lane & 31, lh = lane >> 5;

  const int ar = tid >> 2, ac = tid & 3;
  const __bf16* At = Abf + (size_t)(row0 + ar) * 512 + ac * 8;
  const __bf16* Rt = Rbf + (size_t)(row0 + ar) * 512 + ac * 8;  // MODE1 only
  const __bf16* Bt = Bp + (size_t)colblk * (128 * 512);
  const int aoff = ar * 32 + ((ac ^ (ar & 3)) << 3);

  v16f acc[2];
#pragma unroll
  for (int j = 0; j < 2; j++)
#pragma unroll
    for (int q = 0; q < 16; q++) acc[j][q] = 0.f;

  uint4 ra, rr, rb0, rb1;
  rr = make_uint4(0, 0, 0, 0);

  auto gload = [&](int kt) {
    ra = *(const uint4*)(At + kt * 32);
    if constexpr (MODE == 1) rr = *(const uint4*)(Rt + kt * 32);
    rb0 = *(const uint4*)(Bt + (size_t)kt * 4096 + (size_t)tid * 8);
    rb1 = *(const uint4*)(Bt + (size_t)kt * 4096 + (size_t)(256 + tid) * 8);
  };
  auto lstore = [&](int buf) {
    __bf16* base = smem + buf * BUFS;
    *(uint4*)&base[aoff] = ra;
    if constexpr (MODE == 1) *(uint4*)&base[6144 + aoff] = rr;
    *(uint4*)&base[2048 + (size_t)tid * 8] = rb0;
    *(uint4*)&base[2048 + (size_t)(256 + tid) * 8] = rb1;
  };
  auto compute = [&](int buf) {
    const __bf16* base = smem + buf * BUFS;
#pragma unroll
    for (int ks = 0; ks < 2; ks++) {
      int kc = ks * 2 + lh;
      int fr = wr + l31;
      v8bf a = *(const v8bf*)&base[fr * 32 + ((kc ^ (fr & 3)) << 3)];
      if constexpr (MODE == 1) {
        v8bf r = *(const v8bf*)&base[6144 + fr * 32 + ((kc ^ (fr & 3)) << 3)];
#pragma unroll
        for (int q = 0; q < 8; q++) a[q] = (__bf16)((float)a[q] * (float)r[q]);
      }
#pragma unroll
      for (int ni = 0; ni < 2; ni++) {
        int fc = wc + ni * 32 + l31;
        v8bf b = *(const v8bf*)&base[2048 + fc * 32 + ((kc ^ (fc & 3)) << 3)];
        acc[ni] = __builtin_amdgcn_mfma_f32_32x32x16_bf16(a, b, acc[ni], 0, 0, 0);
      }
    }
  };

  gload(0);
  lstore(0);
  gload(1);
  __syncthreads();
#pragma unroll
  for (int kt = 0; kt < 16; kt++) {
    if (kt < 15) lstore((kt + 1) & 1);   // writes the OTHER buffer
    if (kt < 14) gload(kt + 2);          // in-flight across the barrier
    compute(kt & 1);
    if (kt < 15) __syncthreads();
  }

  // ---- extra K=16 mfma: + Ay(Y_t|1) @ Wy(Weff|beff)   (uses buf0 region)
  {
    int row = tid >> 1, half = tid & 1;
    if (tid < 128)
      *(uint4*)&smem[row * 16 + half * 8] =
          *(const uint4*)(Ay + (size_t)(row0 + row) * 16 + half * 8);
    *(uint4*)&smem[2048 + row * 16 + half * 8] =
        *(const uint4*)(Wy + (size_t)colblk * 2048 + (size_t)row * 16 + half * 8);
  }
  __syncthreads();
  {
    v8bf a = *(const v8bf*)&smem[(wr + l31) * 16 + lh * 8];
#pragma unroll
    for (int ni = 0; ni < 2; ni++) {
      v8bf b = *(const v8bf*)&smem[2048 + (wc + ni * 32 + l31) * 16 + lh * 8];
      acc[ni] = __builtin_amdgcn_mfma_f32_32x32x16_bf16(a, b, acc[ni], 0, 0, 0);
    }
  }
  __syncthreads();  // before reusing smem as output stage

  // ---- epilogue. C layout (32x32): col=lane&31, row=(reg&3)+8*(reg>>2)+4*lh
  if constexpr (MODE == 2) {
#pragma unroll
    for (int ni = 0; ni < 2; ni++) {
      int cl = wc + ni * 32 + l31;
#pragma unroll
      for (int reg = 0; reg < 16; reg++) {
        int rg = row0 + wr + (reg & 3) + ((reg >> 2) << 3) + (lh << 2);
        if (rg >= M) continue;
        Ofp[(size_t)rg * 256 + colblk * 128 + cl] = fmaxf(acc[ni][reg], 0.f);
      }
    }
  } else if constexpr (MODE == 0) {
#pragma unroll
    for (int ni = 0; ni < 2; ni++) {
      int cl = wc + ni * 32 + l31;
#pragma unroll
      for (int reg = 0; reg < 16; reg++) {
        int lr = wr + (reg & 3) + ((reg >> 2) << 3) + (lh << 2);
        smem[lr * 128 + cl] = (__bf16)(1.f / (1.f + expf(-acc[ni][reg])));
      }
    }
    __syncthreads();
    int row = tid >> 2, seg = (tid & 3) * 32;
    int rg = row0 + row;
    if (rg < M) {
      __bf16* dst = (colblk < 4) ? Obf : ObfR;
      int cof = (colblk & 3) * 128;
#pragma unroll
      for (int q = 0; q < 4; q++) {
        uint4 v = *(const uint4*)&smem[row * 128 + seg + q * 8];
        *(uint4*)(dst + (size_t)rg * 512 + cof + seg + q * 8) = v;
      }
    }
  } else {  // MODE 1: ht via fp32 LDS; z/hold coalesced row-linear
    float* smemF = (float*)smem;
#pragma unroll
    for (int ni = 0; ni < 2; ni++) {
      int cl = wc + ni * 32 + l31;
#pragma unroll
      for (int reg = 0; reg < 16; reg++) {
        int lr = wr + (reg & 3) + ((reg >> 2) << 3) + (lh << 2);
        smemF[lr * 128 + cl] = tanhf(acc[ni][reg]);
      }
    }
    __syncthreads();
    int row = tid >> 2, seg = (tid & 3) * 32;
    int rg = row0 + row;
    if (rg < M) {
      int cg0 = colblk * 128 + seg;
#pragma unroll
      for (int q = 0; q < 4; q++) {
        v8bf z8 = *(const v8bf*)(Zbf + (size_t)rg * 512 + cg0 + q * 8);
        v8bf h8 = *(const v8bf*)(Abf + (size_t)rg * 512 + cg0 + q * 8);
        v8bf o;
#pragma unroll
        for (int j = 0; j < 8; j++) {
          float z = (float)z8[j];
          float ht = smemF[row * 128 + seg + q * 8 + j];
          o[j] = (__bf16)(z * (float)h8[j] + (1.f - z) * ht);
        }
        *(v8bf*)(Obf + (size_t)rg * 512 + cg0 + q * 8) = o;
      }
    }
  }
}

// acc[i,c] = sum_t probs[t] * hist[t+1][i,c];  accRelu = bf16(relu(acc))
__global__ void k_acc(const __bf16* __restrict__ hist, const float* __restrict__ probs,
                      float* __restrict__ acc, __bf16* __restrict__ accRelu, int n) {
  int idx = blockIdx.x * blockDim.x + threadIdx.x;
  if (idx >= n * 64) return;
  size_t off = (size_t)idx * 8;
  size_t S = (size_t)n * 512;
  float s[8] = {0, 0, 0, 0, 0, 0, 0, 0};
#pragma unroll
  for (int t = 0; t < TT; t++) {
    float p = probs[t];
    v8bf h = *(const v8bf*)(hist + (size_t)(t + 1) * S + off);
#pragma unroll
    for (int j = 0; j < 8; j++) s[j] = fmaf(p, (float)h[j], s[j]);
  }
  *(float4*)(acc + off) = make_float4(s[0], s[1], s[2], s[3]);
  *(float4*)(acc + off + 4) = make_float4(s[4], s[5], s[6], s[7]);
  v8bf rl;
#pragma unroll
  for (int j = 0; j < 8; j++) rl[j] = (__bf16)fmaxf(s[j], 0.f);
  *(v8bf*)(accRelu + off) = rl;
}

__global__ void k_head2(const float* __restrict__ T1, const float* __restrict__ W2,
                        const float* __restrict__ b2, float* __restrict__ out0, int M) {
  int idx = blockIdx.x * blockDim.x + threadIdx.x;
  if (idx >= M * 12) return;
  int i = idx / 12, c = idx % 12;
  const float* tr = T1 + (size_t)i * 256;
  float s = b2[c];
  for (int k = 0; k < 256; k++) s = fmaf(tr[k], W2[k * 12 + c], s);
  out0[idx] = s;
}

// ---------------- launch ----------------

extern "C" void kernel_launch(void* const* d_in, const int* in_sizes, int n_in,
                              void* d_out, int out_size, void* d_ws, size_t ws_size,
                              hipStream_t stream) {
  const float* x   = (const float*)d_in[0];
  const int*   ei  = (const int*)d_in[1];
  const float* ea  = (const float*)d_in[2];
  const float* att = (const float*)d_in[3];
  const float* Wzg = (const float*)d_in[4];  const float* bzg = (const float*)d_in[5];
  const float* Wzl = (const float*)d_in[6];  const float* bzl = (const float*)d_in[7];
  const float* Wrg = (const float*)d_in[8];  const float* brg = (const float*)d_in[9];
  const float* Wrl = (const float*)d_in[10]; const float* brl = (const float*)d_in[11];
  const float* Whg = (const float*)d_in[12]; const float* bhg = (const float*)d_in[13];
  const float* Whl = (const float*)d_in[14]; const float* bhl = (const float*)d_in[15];
  const float* W1  = (const float*)d_in[16]; const float* b1  = (const float*)d_in[17];
  const float* W2  = (const float*)d_in[18]; const float* b2  = (const float*)d_in[19];

  const int N = in_sizes[0] / NF;
  const int E = in_sizes[1] / 2;
  const int* srcI = ei;
  const int* dstI = ei + E;

  float* out0 = (float*)d_out;                   // [N,12]
  float* accO = (float*)d_out + (size_t)N * 12;  // [N,512] = H_accum (output 1)

  char* wp = (char*)d_ws;
  auto carve = [&](size_t bytes) -> void* {
    void* p = (void*)wp;
    wp += (bytes + 255) & ~(size_t)255;
    return p;
  };
  float*  deg     = (float*)carve((size_t)N * 4);
  float*  dinv    = (float*)carve((size_t)N * 4);
  float*  probs   = (float*)carve(64);
  float*  Y       = (float*)carve((size_t)N * NF * 4);
  __bf16* WzrP    = (__bf16*)carve((size_t)1024 * 512 * 2);
  __bf16* WhP     = (__bf16*)carve((size_t)512 * 512 * 2);
  __bf16* W1P     = (__bf16*)carve((size_t)256 * 512 * 2);
  float*  Wzr_eff = (float*)carve((size_t)4 * 1024 * 4);
  float*  bzr_eff = (float*)carve((size_t)1024 * 4);
  float*  Wh_eff  = (float*)carve((size_t)4 * 512 * 4);
  float*  bh_eff  = (float*)carve((size_t)512 * 4);
  __bf16* hist    = (__bf16*)carve((size_t)(TT + 1) * N * 512 * 2);  // H_0..H_12 bf16
  __bf16* Zbf     = (__bf16*)carve((size_t)N * 512 * 2);
  __bf16* Rbf     = (__bf16*)carve((size_t)N * 512 * 2);
  __bf16* accRelu = (__bf16*)carve((size_t)N * 512 * 2);
  float*  T1      = (float*)carve((size_t)N * 256 * 4);
  __bf16* Ya      = (__bf16*)carve((size_t)TT * N * 16 * 2);
  __bf16* WyZR    = (__bf16*)carve((size_t)1024 * 16 * 2);
  __bf16* WyH     = (__bf16*)carve((size_t)512 * 16 * 2);
  __bf16* Wy1     = (__bf16*)carve((size_t)256 * 16 * 2);
  int*    cnt     = (int*)carve((size_t)2 * N * 4);  // cnt[N] + fill[N] contiguous
  int*    fill    = cnt + N;
  int*    offs    = (int*)carve((size_t)(N + 1) * 4);
  int*    pscan   = (int*)carve((size_t)N * 4);
  int*    bsum    = (int*)carve(256);
  int*    bpre    = (int*)carve(256);
  int*    csrc    = (int*)carve((size_t)E * 4);
  float*  cw      = (float*)carve((size_t)E * 4);
  (void)carve(512 * 1024);  // tail pad: OOB tile reads stay inside ws
  (void)ws_size; (void)n_in; (void)out_size;

  const int TPB = 256;
  auto cdiv = [](int a, int b) { return (a + b - 1) / b; };
  const size_t S = (size_t)N * 512;

  // degree + CSR counts
  k_init<<<cdiv(N, TPB), TPB, 0, stream>>>(deg, cnt, N);
  k_edge<<<cdiv(E, TPB), TPB, 0, stream>>>(dstI, ea, deg, cnt, E);
  k_dinv<<<cdiv(N, TPB), TPB, 0, stream>>>(deg, dinv, N);

  // hierarchical scan -> offs; place; gather Y = Ahat @ X
  const int nb = cdiv(N, 256);
  k_scan1<<<nb, 256, 0, stream>>>(cnt, pscan, bsum, N);
  k_scan2<<<1, 64, 0, stream>>>(bsum, bpre, nb);
  k_scan3<<<cdiv(N, TPB), TPB, 0, stream>>>(pscan, bpre, offs, N, E);
  k_place<<<cdiv(E, TPB), TPB, 0, stream>>>(srcI, dstI, ea, offs, fill, csrc, cw, E);
  k_gather<<<cdiv(N * 12, TPB), TPB, 0, stream>>>(offs, csrc, cw, dinv, x, Y, N);

  // weight prep (LDS-tiled coalesced transposes into swizzled pack)
  {
    dim3 gzr(16, 8); k_pack<0><<<gzr, 256, 0, stream>>>(Wzl, Wrl, WzrP);
    dim3 gh(8, 8);   k_pack<1><<<gh, 256, 0, stream>>>(Whl, nullptr, WhP);
    dim3 g1(4, 8);   k_pack<2><<<g1, 256, 0, stream>>>(W1, nullptr, W1P);
  }
  k_build_eff3<<<cdiv(3 * 5 * 512, TPB), TPB, 0, stream>>>(
      Wzg, Wzl, bzg, bzl, Wrg, Wrl, brg, brl, Whg, Whl, bhg, bhl,
      Wzr_eff, bzr_eff, Wh_eff, bh_eff);
  k_softmax_att<<<1, 64, 0, stream>>>(att, probs);
  k_wy3<<<cdiv((1024 + 512 + 256) * 16, TPB), TPB, 0, stream>>>(
      Wzr_eff, bzr_eff, Wh_eff, bh_eff, b1, WyZR, WyH, Wy1);
  k_ya<<<cdiv(TT * N * 16, TPB), TPB, 0, stream>>>(Y, Ya, N);

  // t=0 shortcut: H1 = (1-sigmoid(Yz)) * tanh(Yh)
  k_t0<<<cdiv(N * 512, TPB), TPB, 0, stream>>>(Y, Wzr_eff, bzr_eff, Wh_eff, bh_eff,
                                               hist + S, N);

  const int RB = cdiv(N, 64);          // 157 row blocks
  const int nGrp = cdiv(RB, 8);        // 20 groups
  for (int t = 1; t < TT; t++) {
    const __bf16* Hbt = hist + (size_t)t * S;
    __bf16* Hbn = hist + (size_t)(t + 1) * S;
    const __bf16* Yat = Ya + (size_t)t * N * 16;
    k_mm<0><<<64 * nGrp, 256, 0, stream>>>(Hbt, WzrP, nullptr, nullptr, Yat, WyZR,
                                           nullptr, Zbf, Rbf, N, RB);
    k_mm<1><<<32 * nGrp, 256, 0, stream>>>(Hbt, WhP, Rbf, Zbf, Yat, WyH,
                                           nullptr, Hbn, nullptr, N, RB);
  }

  // H_accum = sum_t p_t H_{t+1}; head
  k_acc<<<cdiv(N * 64, TPB), TPB, 0, stream>>>(hist, probs, accO, accRelu, N);
  k_mm<2><<<16 * nGrp, 256, 0, stream>>>(accRelu, W1P, nullptr, nullptr, Ya, Wy1,
                                         T1, nullptr, nullptr, N, RB);
  k_head2<<<cdiv(N * 12, TPB), TPB, 0, stream>>>(T1, W2, b2, out0, N);
}

// Round 13
// 811.681 us; speedup vs baseline: 1.2712x; 1.0378x over previous
//
#include <hip/hip_runtime.h>
#include <math.h>

// F=4, T=12, C=512, HID=256, OUT=12
#define NF 48
#define TT 12

typedef __bf16 v8bf __attribute__((ext_vector_type(8)));
typedef float v16f __attribute__((ext_vector_type(16)));

// ---------------- small prep kernels ----------------

// deg=1, cnt=0, fill=0 in one pass
__global__ void k_init(float* __restrict__ deg, int* __restrict__ cnt, int n) {
  int i = blockIdx.x * blockDim.x + threadIdx.x;
  if (i < n) { deg[i] = 1.0f; cnt[i] = 0; cnt[n + i] = 0; }
}

// merged: deg += w  and  cnt += 1  per edge
__global__ void k_edge(const int* __restrict__ dst, const float* __restrict__ w,
                       float* __restrict__ deg, int* __restrict__ cnt, int e) {
  int i = blockIdx.x * blockDim.x + threadIdx.x;
  if (i < e) {
    int d = dst[i];
    atomicAdd(&deg[d], w[i]);
    atomicAdd(&cnt[d], 1);
  }
}

__global__ void k_dinv(const float* __restrict__ deg, float* __restrict__ dinv, int n) {
  int i = blockIdx.x * blockDim.x + threadIdx.x;
  if (i < n) dinv[i] = rsqrtf(fmaxf(deg[i], 1e-12f));
}

__global__ void k_zeroi(int* __restrict__ p, int n) {
  int i = blockIdx.x * blockDim.x + threadIdx.x;
  if (i < n) p[i] = 0;
}

// ---------------- hierarchical scan ----------------

__global__ void k_scan1(const int* __restrict__ cnt, int* __restrict__ pscan,
                        int* __restrict__ bsum, int n) {
  __shared__ int s[256];
  int i = blockIdx.x * 256 + threadIdx.x;
  int v = (i < n) ? cnt[i] : 0;
  s[threadIdx.x] = v;
  __syncthreads();
  for (int off = 1; off < 256; off <<= 1) {
    int t = 0;
    if (threadIdx.x >= off) t = s[threadIdx.x - off];
    __syncthreads();
    s[threadIdx.x] += t;
    __syncthreads();
  }
  if (i < n) pscan[i] = s[threadIdx.x] - v;
  if (threadIdx.x == 255) bsum[blockIdx.x] = s[255];
}

// block-prefix scan + att softmax in one tiny launch
__global__ void k_scan2(const int* __restrict__ bsum, int* __restrict__ bpre, int nb,
                        const float* __restrict__ att, float* __restrict__ probs) {
  if (blockIdx.x == 0 && threadIdx.x == 0) {
    int run = 0;
    for (int b = 0; b < nb; b++) { bpre[b] = run; run += bsum[b]; }
  }
  if (blockIdx.x == 0 && threadIdx.x == 64) {
    float m = -1e30f;
    for (int t = 0; t < TT; t++) m = fmaxf(m, att[t]);
    float e[TT], s = 0.f;
    for (int t = 0; t < TT; t++) { e[t] = expf(att[t] - m); s += e[t]; }
    for (int t = 0; t < TT; t++) probs[t] = e[t] / s;
  }
}

__global__ void k_scan3(const int* __restrict__ pscan, const int* __restrict__ bpre,
                        int* __restrict__ offs, int n, int e) {
  int i = blockIdx.x * blockDim.x + threadIdx.x;
  if (i < n) offs[i] = pscan[i] + bpre[i >> 8];
  if (i == 0) offs[n] = e;
}

__global__ void k_place(const int* __restrict__ src, const int* __restrict__ dst,
                        const float* __restrict__ w, const int* __restrict__ offs,
                        int* __restrict__ fill, int* __restrict__ csrc,
                        float* __restrict__ cw, int e) {
  int i = blockIdx.x * blockDim.x + threadIdx.x;
  if (i >= e) return;
  int d = dst[i];
  int p = offs[d] + atomicAdd(&fill[d], 1);
  csrc[p] = src[i];
  cw[p] = w[i];
}

__global__ void k_gather(const int* __restrict__ offs, const int* __restrict__ csrc,
                         const float* __restrict__ cw, const float* __restrict__ dinv,
                         const float* __restrict__ x, float* __restrict__ Y, int n) {
  int tg = blockIdx.x * blockDim.x + threadIdx.x;
  if (tg >= n * 12) return;
  int i = tg / 12, q = tg % 12;
  float di = dinv[i];
  const float4* x4 = (const float4*)x;
  float4 sv = x4[(size_t)i * 12 + q];
  float ax = di * sv.x, ay = di * sv.y, az = di * sv.z, aw = di * sv.w;
  int e1 = offs[i + 1];
  for (int e = offs[i]; e < e1; e++) {
    int s = csrc[e];
    float wv = cw[e] * dinv[s];
    float4 xv = x4[(size_t)s * 12 + q];
    ax = fmaf(wv, xv.x, ax); ay = fmaf(wv, xv.y, ay);
    az = fmaf(wv, xv.z, az); aw = fmaf(wv, xv.w, aw);
  }
  float4 o = make_float4(di * ax, di * ay, di * az, di * aw);
  ((float4*)Y)[(size_t)i * 12 + q] = o;
}

// ---------------- weight prep: LDS-tiled transpose into swizzled pack ----------------
// pack layout: [n/128][k/32][ row=n%128 ][ chunk(16B)^(row&3) ][ e ]   (verified R7-R11)
__device__ __forceinline__ size_t packIdx128(int n, int k) {
  int row = n & 127;
  int c = (k & 31) >> 3;
  return (size_t)(n >> 7) * (128 * 512) + (size_t)(k >> 5) * (128 * 32) +
         (size_t)row * 32 + (size_t)((c ^ (row & 3)) << 3) + (k & 7);
}

// MODEW 0: zr (Nout=1024, cols n<512 from Wzl bottom, else Wrl bottom)
// MODEW 1: h  (Nout=512, Whl bottom)    MODEW 2: W1 (Nout=256, plain)
template <int MODEW>
__global__ void k_pack(const float* __restrict__ s0, const float* __restrict__ s1,
                       __bf16* __restrict__ WT) {
  __shared__ __bf16 t[64][72];
  int n0 = blockIdx.x * 64, k0 = blockIdx.y * 64;
#pragma unroll
  for (int p = 0; p < 4; p++) {
    int kk = p * 16 + (threadIdx.x >> 4);
    int nn = (threadIdx.x & 15) * 4;
    int n = n0 + nn, k = k0 + kk;
    float4 v;
    if constexpr (MODEW == 2) {
      v = *(const float4*)(s0 + (size_t)k * 256 + n);
    } else {
      const float* src = s0;
      int nc = n;
      if (MODEW == 0 && n >= 512) { src = s1; nc = n - 512; }
      v = *(const float4*)(src + (size_t)(512 + k) * 512 + nc);
    }
    t[kk][nn + 0] = (__bf16)v.x; t[kk][nn + 1] = (__bf16)v.y;
    t[kk][nn + 2] = (__bf16)v.z; t[kk][nn + 3] = (__bf16)v.w;
  }
  __syncthreads();
#pragma unroll
  for (int u = 0; u < 2; u++) {
    int unit = threadIdx.x * 2 + u;
    int nl = unit >> 3, kg = unit & 7;
    v8bf o;
#pragma unroll
    for (int j = 0; j < 8; j++) o[j] = t[kg * 8 + j][nl];
    *(v8bf*)(WT + packIdx128(n0 + nl, k0 + kg * 8)) = o;
  }
}

// all three gate folds in one launch: seg 0: z (->Wzr_eff@0), 1: r (@512), 2: h
__global__ void k_build_eff3(const float* __restrict__ Wzg, const float* __restrict__ Wzl,
                             const float* __restrict__ bzg, const float* __restrict__ bzl,
                             const float* __restrict__ Wrg, const float* __restrict__ Wrl,
                             const float* __restrict__ brg, const float* __restrict__ brl,
                             const float* __restrict__ Whg, const float* __restrict__ Whl,
                             const float* __restrict__ bhg, const float* __restrict__ bhl,
                             float* __restrict__ WzrE, float* __restrict__ bzrE,
                             float* __restrict__ WhE, float* __restrict__ bhE) {
  int idx = blockIdx.x * blockDim.x + threadIdx.x;
  if (idx >= 3 * 5 * 512) return;
  int seg = idx / 2560;
  int r = (idx % 2560) / 512, c = idx % 512;
  const float *Wg, *Wl, *bg, *bl;
  float *We, *be;
  int ostride, ooff;
  if (seg == 0) { Wg = Wzg; Wl = Wzl; bg = bzg; bl = bzl; We = WzrE; be = bzrE; ostride = 1024; ooff = 0; }
  else if (seg == 1) { Wg = Wrg; Wl = Wrl; bg = brg; bl = brl; We = WzrE; be = bzrE; ostride = 1024; ooff = 512; }
  else { Wg = Whg; Wl = Whl; bg = bhg; bl = bhl; We = WhE; be = bhE; ostride = 512; ooff = 0; }
  float s = 0.f;
  if (r < 4) {
    for (int k = 0; k < 512; k++) s += Wg[r * 512 + k] * Wl[k * 512 + c];
    We[r * ostride + ooff + c] = s;
  } else {
    for (int k = 0; k < 512; k++) s += bg[k] * Wl[k * 512 + c];
    be[ooff + c] = s + bl[c];
  }
}

// Wy mini-tiles [n/128][row][k<16]: rows 0..3 = Weff, row4 = beff, rest 0.
__global__ void k_wy3(const float* __restrict__ WzrE, const float* __restrict__ bzrE,
                      const float* __restrict__ WhE, const float* __restrict__ bhE,
                      const float* __restrict__ b1,
                      __bf16* __restrict__ WyZR, __bf16* __restrict__ WyH,
                      __bf16* __restrict__ Wy1) {
  int idx = blockIdx.x * blockDim.x + threadIdx.x;
  const float* Weff; const float* beff; __bf16* out; int Nout, loc;
  if (idx < 1024 * 16) { Weff = WzrE; beff = bzrE; out = WyZR; Nout = 1024; loc = idx; }
  else if (idx < (1024 + 512) * 16) { Weff = WhE; beff = bhE; out = WyH; Nout = 512; loc = idx - 1024 * 16; }
  else if (idx < (1024 + 512 + 256) * 16) { Weff = nullptr; beff = b1; out = Wy1; Nout = 256; loc = idx - (1024 + 512) * 16; }
  else return;
  int n = loc >> 4, k = loc & 15;
  float v = 0.f;
  if (k < 4) v = Weff ? Weff[k * Nout + n] : 0.f;
  else if (k == 4) v = beff[n];
  out[(size_t)(n >> 7) * 2048 + (size_t)(n & 127) * 16 + k] = (__bf16)v;
}

// Ya[t][n][16]: cols 0..3 = Y[n, f, t], col4 = 1, rest 0.
__global__ void k_ya(const float* __restrict__ Y, __bf16* __restrict__ out, int n) {
  int idx = blockIdx.x * blockDim.x + threadIdx.x;
  if (idx >= TT * n * 16) return;
  int t = idx / (n * 16);
  int r = idx % (n * 16);
  int nn = r >> 4, k = r & 15;
  float v = 0.f;
  if (k < 4) v = Y[(size_t)nn * NF + k * TT + t];
  else if (k == 4) v = 1.f;
  out[idx] = (__bf16)v;
}

// t=0 shortcut: H0=0 => z=sigmoid(Yz), ht=tanh(Yh), H1=(1-z)*ht, elementwise (fp32)
__global__ void k_t0(const float* __restrict__ Y,
                     const float* __restrict__ WzrE, const float* __restrict__ bzrE,
                     const float* __restrict__ WhE, const float* __restrict__ bhE,
                     __bf16* __restrict__ H1, int n) {
  int idx = blockIdx.x * blockDim.x + threadIdx.x;
  if (idx >= n * 512) return;
  int i = idx >> 9, c = idx & 511;
  float y0 = Y[(size_t)i * NF + 0], y1 = Y[(size_t)i * NF + 12];
  float y2 = Y[(size_t)i * NF + 24], y3 = Y[(size_t)i * NF + 36];
  float pz = bzrE[c] + y0 * WzrE[c] + y1 * WzrE[1024 + c] +
             y2 * WzrE[2048 + c] + y3 * WzrE[3072 + c];
  float ph = bhE[c] + y0 * WhE[c] + y1 * WhE[512 + c] +
             y2 * WhE[1024 + c] + y3 * WhE[1536 + c];
  float z = 1.f / (1.f + expf(-pz));
  H1[idx] = (__bf16)((1.f - z) * tanhf(ph));
}

// ---------------- MFMA GEMM: 64x128 tile, 32x32x16, dbuf LDS, 1 barrier/iter ----------------
// R12 core (r-multiply at staging, 24 KB LDS, 6 blocks/CU) with the MODE1
// epilogue FIXED: two 32-row passes so the fp32 ht region is 32x128 = 16 KB
// (R12 wrote a 64x128 fp32 tile = 32 KB into 24 KB LDS -> OOB -> wrong H).
template <int MODE>
__global__ __launch_bounds__(256, 6) void k_mm(
    const __bf16* __restrict__ Abf, const __bf16* __restrict__ Bp,
    const __bf16* __restrict__ Rbf, const __bf16* __restrict__ Zbf,
    const __bf16* __restrict__ Ay, const __bf16* __restrict__ Wy,
    float* __restrict__ Ofp, __bf16* __restrict__ Obf, __bf16* __restrict__ ObfR,
    int M, int RB) {
  constexpr int CB = (MODE == 0) ? 8 : (MODE == 1) ? 4 : 2;
  constexpr int BUFS = 6144;  // elems per LDS buffer: A 2048 + B 4096
  __shared__ __bf16 smem[12288];

  int s = blockIdx.x;
  int grp = 8 * CB;
  int local = s % grp;
  int rowblk = (s / grp) * 8 + (local & 7);
  int colblk = local >> 3;
  if (rowblk >= RB) return;
  const int row0 = rowblk * 64;

  const int tid = threadIdx.x;
  const int lane = tid & 63, w = tid >> 6;
  const int wr = (w >> 1) * 32, wc = (w & 1) * 64;
  const int l31 = lane & 31, lh = lane >> 5;

  const int ar = tid >> 2, ac = tid & 3;
  const __bf16* At = Abf + (size_t)(row0 + ar) * 512 + ac * 8;
  const __bf16* Rt = Rbf + (size_t)(row0 + ar) * 512 + ac * 8;  // MODE1 only
  const __bf16* Bt = Bp + (size_t)colblk * (128 * 512);
  const int aoff = ar * 32 + ((ac ^ (ar & 3)) << 3);

  v16f acc[2];
#pragma unroll
  for (int j = 0; j < 2; j++)
#pragma unroll
    for (int q = 0; q < 16; q++) acc[j][q] = 0.f;

  uint4 ra, rr, rb0, rb1;
  rr = make_uint4(0, 0, 0, 0);

  auto gload = [&](int kt) {
    ra = *(const uint4*)(At + kt * 32);
    if constexpr (MODE == 1) rr = *(const uint4*)(Rt + kt * 32);
    rb0 = *(const uint4*)(Bt + (size_t)kt * 4096 + (size_t)tid * 8);
    rb1 = *(const uint4*)(Bt + (size_t)kt * 4096 + (size_t)(256 + tid) * 8);
  };
  auto lstore = [&](int buf) {
    __bf16* base = smem + buf * BUFS;
    if constexpr (MODE == 1) {
      // multiply r into A at staging (once per element)
      v8bf h = *(const v8bf*)&ra;
      v8bf r = *(const v8bf*)&rr;
      v8bf o;
#pragma unroll
      for (int q = 0; q < 8; q++) o[q] = (__bf16)((float)h[q] * (float)r[q]);
      *(v8bf*)&base[aoff] = o;
    } else {
      *(uint4*)&base[aoff] = ra;
    }
    *(uint4*)&base[2048 + (size_t)tid * 8] = rb0;
    *(uint4*)&base[2048 + (size_t)(256 + tid) * 8] = rb1;
  };
  auto compute = [&](int buf) {
    const __bf16* base = smem + buf * BUFS;
#pragma unroll
    for (int ks = 0; ks < 2; ks++) {
      int kc = ks * 2 + lh;
      int fr = wr + l31;
      v8bf a = *(const v8bf*)&base[fr * 32 + ((kc ^ (fr & 3)) << 3)];
#pragma unroll
      for (int ni = 0; ni < 2; ni++) {
        int fc = wc + ni * 32 + l31;
        v8bf b = *(const v8bf*)&base[2048 + fc * 32 + ((kc ^ (fc & 3)) << 3)];
        acc[ni] = __builtin_amdgcn_mfma_f32_32x32x16_bf16(a, b, acc[ni], 0, 0, 0);
      }
    }
  };

  gload(0);
  lstore(0);
  gload(1);
  __syncthreads();
#pragma unroll
  for (int kt = 0; kt < 16; kt++) {
    if (kt < 15) lstore((kt + 1) & 1);   // writes the OTHER buffer
    if (kt < 14) gload(kt + 2);          // in-flight across the barrier
    compute(kt & 1);
    if (kt < 15) __syncthreads();
  }

  // ---- extra K=16 mfma: + Ay(Y_t|1) @ Wy(Weff|beff)   (uses buf0 region)
  {
    int row = tid >> 1, half = tid & 1;
    if (tid < 128)
      *(uint4*)&smem[row * 16 + half * 8] =
          *(const uint4*)(Ay + (size_t)(row0 + row) * 16 + half * 8);
    *(uint4*)&smem[2048 + row * 16 + half * 8] =
        *(const uint4*)(Wy + (size_t)colblk * 2048 + (size_t)row * 16 + half * 8);
  }
  __syncthreads();
  {
    v8bf a = *(const v8bf*)&smem[(wr + l31) * 16 + lh * 8];
#pragma unroll
    for (int ni = 0; ni < 2; ni++) {
      v8bf b = *(const v8bf*)&smem[2048 + (wc + ni * 32 + l31) * 16 + lh * 8];
      acc[ni] = __builtin_amdgcn_mfma_f32_32x32x16_bf16(a, b, acc[ni], 0, 0, 0);
    }
  }
  __syncthreads();  // before reusing smem as output stage

  // ---- epilogue. C layout (32x32): col=lane&31, row=(reg&3)+8*(reg>>2)+4*lh
  if constexpr (MODE == 2) {
#pragma unroll
    for (int ni = 0; ni < 2; ni++) {
      int cl = wc + ni * 32 + l31;
#pragma unroll
      for (int reg = 0; reg < 16; reg++) {
        int rg = row0 + wr + (reg & 3) + ((reg >> 2) << 3) + (lh << 2);
        if (rg >= M) continue;
        Ofp[(size_t)rg * 256 + colblk * 128 + cl] = fmaxf(acc[ni][reg], 0.f);
      }
    }
  } else if constexpr (MODE == 0) {
#pragma unroll
    for (int ni = 0; ni < 2; ni++) {
      int cl = wc + ni * 32 + l31;
#pragma unroll
      for (int reg = 0; reg < 16; reg++) {
        int lr = wr + (reg & 3) + ((reg >> 2) << 3) + (lh << 2);
        smem[lr * 128 + cl] = (__bf16)(1.f / (1.f + expf(-acc[ni][reg])));
      }
    }
    __syncthreads();
    int row = tid >> 2, seg = (tid & 3) * 32;
    int rg = row0 + row;
    if (rg < M) {
      __bf16* dst = (colblk < 4) ? Obf : ObfR;
      int cof = (colblk & 3) * 128;
#pragma unroll
      for (int q = 0; q < 4; q++) {
        uint4 v = *(const uint4*)&smem[row * 128 + seg + q * 8];
        *(uint4*)(dst + (size_t)rg * 512 + cof + seg + q * 8) = v;
      }
    }
  } else {  // MODE 1: two 32-row passes; fp32 ht region = 32x128 = 16 KB (fits 24 KB)
    float* sF = (float*)smem;
#pragma unroll
    for (int h = 0; h < 2; h++) {
      if ((w >> 1) == h) {
#pragma unroll
        for (int ni = 0; ni < 2; ni++) {
          int cl = wc + ni * 32 + l31;
#pragma unroll
          for (int reg = 0; reg < 16; reg++) {
            int lr = (reg & 3) + ((reg >> 2) << 3) + (lh << 2);  // 0..31 local
            sF[lr * 128 + cl] = tanhf(acc[ni][reg]);
          }
        }
      }
      __syncthreads();
      int row = tid >> 3, seg = (tid & 7) * 16;
      int rg = row0 + h * 32 + row;
      if (rg < M) {
        int cg0 = colblk * 128 + seg;
#pragma unroll
        for (int q = 0; q < 2; q++) {
          v8bf z8 = *(const v8bf*)(Zbf + (size_t)rg * 512 + cg0 + q * 8);
          v8bf h8 = *(const v8bf*)(Abf + (size_t)rg * 512 + cg0 + q * 8);
          v8bf o;
#pragma unroll
          for (int j = 0; j < 8; j++) {
            float z = (float)z8[j];
            float ht = sF[row * 128 + seg + q * 8 + j];
            o[j] = (__bf16)(z * (float)h8[j] + (1.f - z) * ht);
          }
          *(v8bf*)(Obf + (size_t)rg * 512 + cg0 + q * 8) = o;
        }
      }
      if (h == 0) __syncthreads();  // protect sF before second-half writes
    }
  }
}

// acc[i,c] = sum_t probs[t] * hist[t+1][i,c];  accRelu = bf16(relu(acc))
__global__ void k_acc(const __bf16* __restrict__ hist, const float* __restrict__ probs,
                      float* __restrict__ acc, __bf16* __restrict__ accRelu, int n) {
  int idx = blockIdx.x * blockDim.x + threadIdx.x;
  if (idx >= n * 64) return;
  size_t off = (size_t)idx * 8;
  size_t S = (size_t)n * 512;
  float s[8] = {0, 0, 0, 0, 0, 0, 0, 0};
#pragma unroll
  for (int t = 0; t < TT; t++) {
    float p = probs[t];
    v8bf h = *(const v8bf*)(hist + (size_t)(t + 1) * S + off);
#pragma unroll
    for (int j = 0; j < 8; j++) s[j] = fmaf(p, (float)h[j], s[j]);
  }
  *(float4*)(acc + off) = make_float4(s[0], s[1], s[2], s[3]);
  *(float4*)(acc + off + 4) = make_float4(s[4], s[5], s[6], s[7]);
  v8bf rl;
#pragma unroll
  for (int j = 0; j < 8; j++) rl[j] = (__bf16)fmaxf(s[j], 0.f);
  *(v8bf*)(accRelu + off) = rl;
}

__global__ void k_head2(const float* __restrict__ T1, const float* __restrict__ W2,
                        const float* __restrict__ b2, float* __restrict__ out0, int M) {
  int idx = blockIdx.x * blockDim.x + threadIdx.x;
  if (idx >= M * 12) return;
  int i = idx / 12, c = idx % 12;
  const float* tr = T1 + (size_t)i * 256;
  float s = b2[c];
  for (int k = 0; k < 256; k++) s = fmaf(tr[k], W2[k * 12 + c], s);
  out0[idx] = s;
}

// ---------------- launch ----------------

extern "C" void kernel_launch(void* const* d_in, const int* in_sizes, int n_in,
                              void* d_out, int out_size, void* d_ws, size_t ws_size,
                              hipStream_t stream) {
  const float* x   = (const float*)d_in[0];
  const int*   ei  = (const int*)d_in[1];
  const float* ea  = (const float*)d_in[2];
  const float* att = (const float*)d_in[3];
  const float* Wzg = (const float*)d_in[4];  const float* bzg = (const float*)d_in[5];
  const float* Wzl = (const float*)d_in[6];  const float* bzl = (const float*)d_in[7];
  const float* Wrg = (const float*)d_in[8];  const float* brg = (const float*)d_in[9];
  const float* Wrl = (const float*)d_in[10]; const float* brl = (const float*)d_in[11];
  const float* Whg = (const float*)d_in[12]; const float* bhg = (const float*)d_in[13];
  const float* Whl = (const float*)d_in[14]; const float* bhl = (const float*)d_in[15];
  const float* W1  = (const float*)d_in[16]; const float* b1  = (const float*)d_in[17];
  const float* W2  = (const float*)d_in[18]; const float* b2  = (const float*)d_in[19];

  const int N = in_sizes[0] / NF;
  const int E = in_sizes[1] / 2;
  const int* srcI = ei;
  const int* dstI = ei + E;

  float* out0 = (float*)d_out;                   // [N,12]
  float* accO = (float*)d_out + (size_t)N * 12;  // [N,512] = H_accum (output 1)

  char* wp = (char*)d_ws;
  auto carve = [&](size_t bytes) -> void* {
    void* p = (void*)wp;
    wp += (bytes + 255) & ~(size_t)255;
    return p;
  };
  float*  deg     = (float*)carve((size_t)N * 4);
  float*  dinv    = (float*)carve((size_t)N * 4);
  float*  probs   = (float*)carve(64);
  float*  Y       = (float*)carve((size_t)N * NF * 4);
  __bf16* WzrP    = (__bf16*)carve((size_t)1024 * 512 * 2);
  __bf16* WhP     = (__bf16*)carve((size_t)512 * 512 * 2);
  __bf16* W1P     = (__bf16*)carve((size_t)256 * 512 * 2);
  float*  Wzr_eff = (float*)carve((size_t)4 * 1024 * 4);
  float*  bzr_eff = (float*)carve((size_t)1024 * 4);
  float*  Wh_eff  = (float*)carve((size_t)4 * 512 * 4);
  float*  bh_eff  = (float*)carve((size_t)512 * 4);
  __bf16* hist    = (__bf16*)carve((size_t)(TT + 1) * N * 512 * 2);  // H_0..H_12 bf16
  __bf16* Zbf     = (__bf16*)carve((size_t)N * 512 * 2);
  __bf16* Rbf     = (__bf16*)carve((size_t)N * 512 * 2);
  __bf16* accRelu = (__bf16*)carve((size_t)N * 512 * 2);
  float*  T1      = (float*)carve((size_t)N * 256 * 4);
  __bf16* Ya      = (__bf16*)carve((size_t)TT * N * 16 * 2);
  __bf16* WyZR    = (__bf16*)carve((size_t)1024 * 16 * 2);
  __bf16* WyH     = (__bf16*)carve((size_t)512 * 16 * 2);
  __bf16* Wy1     = (__bf16*)carve((size_t)256 * 16 * 2);
  int*    cnt     = (int*)carve((size_t)2 * N * 4);  // cnt[N] + fill[N] contiguous
  int*    fill    = cnt + N;
  int*    offs    = (int*)carve((size_t)(N + 1) * 4);
  int*    pscan   = (int*)carve((size_t)N * 4);
  int*    bsum    = (int*)carve(256);
  int*    bpre    = (int*)carve(256);
  int*    csrc    = (int*)carve((size_t)E * 4);
  float*  cw      = (float*)carve((size_t)E * 4);
  (void)carve(512 * 1024);  // tail pad: OOB tile reads stay inside ws
  (void)ws_size; (void)n_in; (void)out_size;

  const int TPB = 256;
  auto cdiv = [](int a, int b) { return (a + b - 1) / b; };
  const size_t S = (size_t)N * 512;

  // degree + CSR counts
  k_init<<<cdiv(N, TPB), TPB, 0, stream>>>(deg, cnt, N);
  k_edge<<<cdiv(E, TPB), TPB, 0, stream>>>(dstI, ea, deg, cnt, E);
  k_dinv<<<cdiv(N, TPB), TPB, 0, stream>>>(deg, dinv, N);

  // hierarchical scan -> offs; place; gather Y = Ahat @ X
  const int nb = cdiv(N, 256);
  k_scan1<<<nb, 256, 0, stream>>>(cnt, pscan, bsum, N);
  k_scan2<<<1, 128, 0, stream>>>(bsum, bpre, nb, att, probs);
  k_scan3<<<cdiv(N, TPB), TPB, 0, stream>>>(pscan, bpre, offs, N, E);
  k_place<<<cdiv(E, TPB), TPB, 0, stream>>>(srcI, dstI, ea, offs, fill, csrc, cw, E);
  k_gather<<<cdiv(N * 12, TPB), TPB, 0, stream>>>(offs, csrc, cw, dinv, x, Y, N);

  // weight prep (LDS-tiled coalesced transposes into swizzled pack)
  {
    dim3 gzr(16, 8); k_pack<0><<<gzr, 256, 0, stream>>>(Wzl, Wrl, WzrP);
    dim3 gh(8, 8);   k_pack<1><<<gh, 256, 0, stream>>>(Whl, nullptr, WhP);
    dim3 g1(4, 8);   k_pack<2><<<g1, 256, 0, stream>>>(W1, nullptr, W1P);
  }
  k_build_eff3<<<cdiv(3 * 5 * 512, TPB), TPB, 0, stream>>>(
      Wzg, Wzl, bzg, bzl, Wrg, Wrl, brg, brl, Whg, Whl, bhg, bhl,
      Wzr_eff, bzr_eff, Wh_eff, bh_eff);
  k_wy3<<<cdiv((1024 + 512 + 256) * 16, TPB), TPB, 0, stream>>>(
      Wzr_eff, bzr_eff, Wh_eff, bh_eff, b1, WyZR, WyH, Wy1);
  k_ya<<<cdiv(TT * N * 16, TPB), TPB, 0, stream>>>(Y, Ya, N);

  // t=0 shortcut: H1 = (1-sigmoid(Yz)) * tanh(Yh)
  k_t0<<<cdiv(N * 512, TPB), TPB, 0, stream>>>(Y, Wzr_eff, bzr_eff, Wh_eff, bh_eff,
                                               hist + S, N);

  const int RB = cdiv(N, 64);          // 157 row blocks
  const int nGrp = cdiv(RB, 8);        // 20 groups
  for (int t = 1; t < TT; t++) {
    const __bf16* Hbt = hist + (size_t)t * S;
    __bf16* Hbn = hist + (size_t)(t + 1) * S;
    const __bf16* Yat = Ya + (size_t)t * N * 16;
    k_mm<0><<<64 * nGrp, 256, 0, stream>>>(Hbt, WzrP, nullptr, nullptr, Yat, WyZR,
                                           nullptr, Zbf, Rbf, N, RB);
    k_mm<1><<<32 * nGrp, 256, 0, stream>>>(Hbt, WhP, Rbf, Zbf, Yat, WyH,
                                           nullptr, Hbn, nullptr, N, RB);
  }

  // H_accum = sum_t p_t H_{t+1}; head
  k_acc<<<cdiv(N * 64, TPB), TPB, 0, stream>>>(hist, probs, accO, accRelu, N);
  k_mm<2><<<16 * nGrp, 256, 0, stream>>>(accRelu, W1P, nullptr, nullptr, Ya, Wy1,
                                         T1, nullptr, nullptr, N, RB);
  k_head2<<<cdiv(N * 12, TPB), TPB, 0, stream>>>(T1, W2, b2, out0, N);
}

// Round 14
// 796.527 us; speedup vs baseline: 1.2954x; 1.0190x over previous
//
#include <hip/hip_runtime.h>
#include <math.h>

// F=4, T=12, C=512, HID=256, OUT=12
#define NF 48
#define TT 12

typedef __bf16 v8bf __attribute__((ext_vector_type(8)));
typedef float v16f __attribute__((ext_vector_type(16)));

// ---------------- small prep kernels ----------------

// deg=1, cnt=0, fill=0 in one pass
__global__ void k_init(float* __restrict__ deg, int* __restrict__ cnt, int n) {
  int i = blockIdx.x * blockDim.x + threadIdx.x;
  if (i < n) { deg[i] = 1.0f; cnt[i] = 0; cnt[n + i] = 0; }
}

// merged: deg += w  and  cnt += 1  per edge
__global__ void k_edge(const int* __restrict__ dst, const float* __restrict__ w,
                       float* __restrict__ deg, int* __restrict__ cnt, int e) {
  int i = blockIdx.x * blockDim.x + threadIdx.x;
  if (i < e) {
    int d = dst[i];
    atomicAdd(&deg[d], w[i]);
    atomicAdd(&cnt[d], 1);
  }
}

// ---------------- hierarchical scan (+ dinv fused) ----------------

__global__ void k_scan1(const int* __restrict__ cnt, int* __restrict__ pscan,
                        int* __restrict__ bsum, const float* __restrict__ deg,
                        float* __restrict__ dinv, int n) {
  __shared__ int s[256];
  int i = blockIdx.x * 256 + threadIdx.x;
  int v = (i < n) ? cnt[i] : 0;
  s[threadIdx.x] = v;
  __syncthreads();
  for (int off = 1; off < 256; off <<= 1) {
    int t = 0;
    if (threadIdx.x >= off) t = s[threadIdx.x - off];
    __syncthreads();
    s[threadIdx.x] += t;
    __syncthreads();
  }
  if (i < n) {
    pscan[i] = s[threadIdx.x] - v;
    dinv[i] = rsqrtf(fmaxf(deg[i], 1e-12f));
  }
  if (threadIdx.x == 255) bsum[blockIdx.x] = s[255];
}

// block-prefix scan + att softmax in one tiny launch
__global__ void k_scan2(const int* __restrict__ bsum, int* __restrict__ bpre, int nb,
                        const float* __restrict__ att, float* __restrict__ probs) {
  if (blockIdx.x == 0 && threadIdx.x == 0) {
    int run = 0;
    for (int b = 0; b < nb; b++) { bpre[b] = run; run += bsum[b]; }
  }
  if (blockIdx.x == 0 && threadIdx.x == 64) {
    float m = -1e30f;
    for (int t = 0; t < TT; t++) m = fmaxf(m, att[t]);
    float e[TT], s = 0.f;
    for (int t = 0; t < TT; t++) { e[t] = expf(att[t] - m); s += e[t]; }
    for (int t = 0; t < TT; t++) probs[t] = e[t] / s;
  }
}

__global__ void k_scan3(const int* __restrict__ pscan, const int* __restrict__ bpre,
                        int* __restrict__ offs, int n, int e) {
  int i = blockIdx.x * blockDim.x + threadIdx.x;
  if (i < n) offs[i] = pscan[i] + bpre[i >> 8];
  if (i == 0) offs[n] = e;
}

__global__ void k_place(const int* __restrict__ src, const int* __restrict__ dst,
                        const float* __restrict__ w, const int* __restrict__ offs,
                        int* __restrict__ fill, int* __restrict__ csrc,
                        float* __restrict__ cw, int e) {
  int i = blockIdx.x * blockDim.x + threadIdx.x;
  if (i >= e) return;
  int d = dst[i];
  int p = offs[d] + atomicAdd(&fill[d], 1);
  csrc[p] = src[i];
  cw[p] = w[i];
}

__global__ void k_gather(const int* __restrict__ offs, const int* __restrict__ csrc,
                         const float* __restrict__ cw, const float* __restrict__ dinv,
                         const float* __restrict__ x, float* __restrict__ Y, int n) {
  int tg = blockIdx.x * blockDim.x + threadIdx.x;
  if (tg >= n * 12) return;
  int i = tg / 12, q = tg % 12;
  float di = dinv[i];
  const float4* x4 = (const float4*)x;
  float4 sv = x4[(size_t)i * 12 + q];
  float ax = di * sv.x, ay = di * sv.y, az = di * sv.z, aw = di * sv.w;
  int e1 = offs[i + 1];
  for (int e = offs[i]; e < e1; e++) {
    int s = csrc[e];
    float wv = cw[e] * dinv[s];
    float4 xv = x4[(size_t)s * 12 + q];
    ax = fmaf(wv, xv.x, ax); ay = fmaf(wv, xv.y, ay);
    az = fmaf(wv, xv.z, az); aw = fmaf(wv, xv.w, aw);
  }
  float4 o = make_float4(di * ax, di * ay, di * az, di * aw);
  ((float4*)Y)[(size_t)i * 12 + q] = o;
}

// ---------------- weight prep: LDS-tiled transpose into swizzled pack ----------------
// pack layout: [n/128][k/32][ row=n%128 ][ chunk(16B)^(row&3) ][ e ]   (verified R7-R13)
__device__ __forceinline__ size_t packIdx128(int n, int k) {
  int row = n & 127;
  int c = (k & 31) >> 3;
  return (size_t)(n >> 7) * (128 * 512) + (size_t)(k >> 5) * (128 * 32) +
         (size_t)row * 32 + (size_t)((c ^ (row & 3)) << 3) + (k & 7);
}

// one launch, blockIdx.z selects: 0: zr (16x8 blocks), 1: h (8x8), 2: W1 (4x8)
__global__ void k_pack3(const float* __restrict__ Wzl, const float* __restrict__ Wrl,
                        const float* __restrict__ Whl, const float* __restrict__ W1,
                        __bf16* __restrict__ WzrP, __bf16* __restrict__ WhP,
                        __bf16* __restrict__ W1P) {
  __shared__ __bf16 t[64][72];
  int modew = blockIdx.z;
  if (modew == 1 && blockIdx.x >= 8) return;
  if (modew == 2 && blockIdx.x >= 4) return;
  int n0 = blockIdx.x * 64, k0 = blockIdx.y * 64;
  __bf16* WT = (modew == 0) ? WzrP : (modew == 1) ? WhP : W1P;
#pragma unroll
  for (int p = 0; p < 4; p++) {
    int kk = p * 16 + (threadIdx.x >> 4);
    int nn = (threadIdx.x & 15) * 4;
    int n = n0 + nn, k = k0 + kk;
    float4 v;
    if (modew == 2) {
      v = *(const float4*)(W1 + (size_t)k * 256 + n);
    } else {
      const float* src = (modew == 1) ? Whl : Wzl;
      int nc = n;
      if (modew == 0 && n >= 512) { src = Wrl; nc = n - 512; }
      v = *(const float4*)(src + (size_t)(512 + k) * 512 + nc);
    }
    t[kk][nn + 0] = (__bf16)v.x; t[kk][nn + 1] = (__bf16)v.y;
    t[kk][nn + 2] = (__bf16)v.z; t[kk][nn + 3] = (__bf16)v.w;
  }
  __syncthreads();
#pragma unroll
  for (int u = 0; u < 2; u++) {
    int unit = threadIdx.x * 2 + u;
    int nl = unit >> 3, kg = unit & 7;
    v8bf o;
#pragma unroll
    for (int j = 0; j < 8; j++) o[j] = t[kg * 8 + j][nl];
    *(v8bf*)(WT + packIdx128(n0 + nl, k0 + kg * 8)) = o;
  }
}

// all three gate folds in one launch: seg 0: z (->Wzr_eff@0), 1: r (@512), 2: h
__global__ void k_build_eff3(const float* __restrict__ Wzg, const float* __restrict__ Wzl,
                             const float* __restrict__ bzg, const float* __restrict__ bzl,
                             const float* __restrict__ Wrg, const float* __restrict__ Wrl,
                             const float* __restrict__ brg, const float* __restrict__ brl,
                             const float* __restrict__ Whg, const float* __restrict__ Whl,
                             const float* __restrict__ bhg, const float* __restrict__ bhl,
                             float* __restrict__ WzrE, float* __restrict__ bzrE,
                             float* __restrict__ WhE, float* __restrict__ bhE) {
  int idx = blockIdx.x * blockDim.x + threadIdx.x;
  if (idx >= 3 * 5 * 512) return;
  int seg = idx / 2560;
  int r = (idx % 2560) / 512, c = idx % 512;
  const float *Wg, *Wl, *bg, *bl;
  float *We, *be;
  int ostride, ooff;
  if (seg == 0) { Wg = Wzg; Wl = Wzl; bg = bzg; bl = bzl; We = WzrE; be = bzrE; ostride = 1024; ooff = 0; }
  else if (seg == 1) { Wg = Wrg; Wl = Wrl; bg = brg; bl = brl; We = WzrE; be = bzrE; ostride = 1024; ooff = 512; }
  else { Wg = Whg; Wl = Whl; bg = bhg; bl = bhl; We = WhE; be = bhE; ostride = 512; ooff = 0; }
  float s = 0.f;
  if (r < 4) {
    for (int k = 0; k < 512; k++) s += Wg[r * 512 + k] * Wl[k * 512 + c];
    We[r * ostride + ooff + c] = s;
  } else {
    for (int k = 0; k < 512; k++) s += bg[k] * Wl[k * 512 + c];
    be[ooff + c] = s + bl[c];
  }
}

// Wy mini-tiles [n/128][row][k<16]: rows 0..3 = Weff, row4 = beff, rest 0.
__global__ void k_wy3(const float* __restrict__ WzrE, const float* __restrict__ bzrE,
                      const float* __restrict__ WhE, const float* __restrict__ bhE,
                      const float* __restrict__ b1,
                      __bf16* __restrict__ WyZR, __bf16* __restrict__ WyH,
                      __bf16* __restrict__ Wy1) {
  int idx = blockIdx.x * blockDim.x + threadIdx.x;
  const float* Weff; const float* beff; __bf16* out; int Nout, loc;
  if (idx < 1024 * 16) { Weff = WzrE; beff = bzrE; out = WyZR; Nout = 1024; loc = idx; }
  else if (idx < (1024 + 512) * 16) { Weff = WhE; beff = bhE; out = WyH; Nout = 512; loc = idx - 1024 * 16; }
  else if (idx < (1024 + 512 + 256) * 16) { Weff = nullptr; beff = b1; out = Wy1; Nout = 256; loc = idx - (1024 + 512) * 16; }
  else return;
  int n = loc >> 4, k = loc & 15;
  float v = 0.f;
  if (k < 4) v = Weff ? Weff[k * Nout + n] : 0.f;
  else if (k == 4) v = beff[n];
  out[(size_t)(n >> 7) * 2048 + (size_t)(n & 127) * 16 + k] = (__bf16)v;
}

// merged: t=0 shortcut (first n*512 threads) + Ya build (next TT*n*16 threads)
__global__ void k_yat0(const float* __restrict__ Y,
                       const float* __restrict__ WzrE, const float* __restrict__ bzrE,
                       const float* __restrict__ WhE, const float* __restrict__ bhE,
                       __bf16* __restrict__ Ya, __bf16* __restrict__ H1, int n) {
  int idx = blockIdx.x * blockDim.x + threadIdx.x;
  int nt0 = n * 512;
  if (idx < nt0) {
    int i = idx >> 9, c = idx & 511;
    float y0 = Y[(size_t)i * NF + 0], y1 = Y[(size_t)i * NF + 12];
    float y2 = Y[(size_t)i * NF + 24], y3 = Y[(size_t)i * NF + 36];
    float pz = bzrE[c] + y0 * WzrE[c] + y1 * WzrE[1024 + c] +
               y2 * WzrE[2048 + c] + y3 * WzrE[3072 + c];
    float ph = bhE[c] + y0 * WhE[c] + y1 * WhE[512 + c] +
               y2 * WhE[1024 + c] + y3 * WhE[1536 + c];
    float z = 1.f / (1.f + expf(-pz));
    H1[idx] = (__bf16)((1.f - z) * tanhf(ph));
  } else {
    int r = idx - nt0;
    if (r >= TT * n * 16) return;
    int t = r / (n * 16);
    int loc = r % (n * 16);
    int nn = loc >> 4, k = loc & 15;
    float v = 0.f;
    if (k < 4) v = Y[(size_t)nn * NF + k * TT + t];
    else if (k == 4) v = 1.f;
    Ya[r] = (__bf16)v;
  }
}

// ---------------- MFMA GEMM: 64x128 tile, 32x32x16, dbuf LDS, 1 barrier/iter ----------------
// R13 core with the Y-term mfma folded into the K-loop as iteration 16
// (removes 2 barriers + the separate Ay/Wy section per dispatch).
template <int MODE>
__global__ __launch_bounds__(256, 6) void k_mm(
    const __bf16* __restrict__ Abf, const __bf16* __restrict__ Bp,
    const __bf16* __restrict__ Rbf, const __bf16* __restrict__ Zbf,
    const __bf16* __restrict__ Ay, const __bf16* __restrict__ Wy,
    float* __restrict__ Ofp, __bf16* __restrict__ Obf, __bf16* __restrict__ ObfR,
    int M, int RB) {
  constexpr int CB = (MODE == 0) ? 8 : (MODE == 1) ? 4 : 2;
  constexpr int BUFS = 6144;  // elems per LDS buffer: A 2048 + B 4096
  __shared__ __bf16 smem[12288];

  int s = blockIdx.x;
  int grp = 8 * CB;
  int local = s % grp;
  int rowblk = (s / grp) * 8 + (local & 7);
  int colblk = local >> 3;
  if (rowblk >= RB) return;
  const int row0 = rowblk * 64;

  const int tid = threadIdx.x;
  const int lane = tid & 63, w = tid >> 6;
  const int wr = (w >> 1) * 32, wc = (w & 1) * 64;
  const int l31 = lane & 31, lh = lane >> 5;

  const int ar = tid >> 2, ac = tid & 3;
  const __bf16* At = Abf + (size_t)(row0 + ar) * 512 + ac * 8;
  const __bf16* Rt = Rbf + (size_t)(row0 + ar) * 512 + ac * 8;  // MODE1 only
  const __bf16* Bt = Bp + (size_t)colblk * (128 * 512);
  const int aoff = ar * 32 + ((ac ^ (ar & 3)) << 3);

  v16f acc[2];
#pragma unroll
  for (int j = 0; j < 2; j++)
#pragma unroll
    for (int q = 0; q < 16; q++) acc[j][q] = 0.f;

  uint4 ra, rr, rb0, rb1;
  rr = make_uint4(0, 0, 0, 0);

  auto gload = [&](int kt) {
    ra = *(const uint4*)(At + kt * 32);
    if constexpr (MODE == 1) rr = *(const uint4*)(Rt + kt * 32);
    rb0 = *(const uint4*)(Bt + (size_t)kt * 4096 + (size_t)tid * 8);
    rb1 = *(const uint4*)(Bt + (size_t)kt * 4096 + (size_t)(256 + tid) * 8);
  };
  // Y-tile loads: Ay 64x16 (tid<128), Wy 128x16 (all threads)
  auto gloadY = [&]() {
    if (tid < 128)
      ra = *(const uint4*)(Ay + (size_t)(row0 + (tid >> 1)) * 16 + (tid & 1) * 8);
    rb0 = *(const uint4*)(Wy + (size_t)colblk * 2048 + (size_t)(tid >> 1) * 16 + (tid & 1) * 8);
  };
  auto lstore = [&](int buf) {
    __bf16* base = smem + buf * BUFS;
    if constexpr (MODE == 1) {
      v8bf h = *(const v8bf*)&ra;
      v8bf r = *(const v8bf*)&rr;
      v8bf o;
#pragma unroll
      for (int q = 0; q < 8; q++) o[q] = (__bf16)((float)h[q] * (float)r[q]);
      *(v8bf*)&base[aoff] = o;
    } else {
      *(uint4*)&base[aoff] = ra;
    }
    *(uint4*)&base[2048 + (size_t)tid * 8] = rb0;
    *(uint4*)&base[2048 + (size_t)(256 + tid) * 8] = rb1;
  };
  auto lstoreY = [&](int buf) {  // linear 16-wide layout; NO r-multiply (Y-term ungated)
    __bf16* base = smem + buf * BUFS;
    if (tid < 128) *(uint4*)&base[(tid >> 1) * 16 + (tid & 1) * 8] = ra;
    *(uint4*)&base[2048 + (size_t)(tid >> 1) * 16 + (tid & 1) * 8] = rb0;
  };
  auto compute = [&](int buf) {
    const __bf16* base = smem + buf * BUFS;
#pragma unroll
    for (int ks = 0; ks < 2; ks++) {
      int kc = ks * 2 + lh;
      int fr = wr + l31;
      v8bf a = *(const v8bf*)&base[fr * 32 + ((kc ^ (fr & 3)) << 3)];
#pragma unroll
      for (int ni = 0; ni < 2; ni++) {
        int fc = wc + ni * 32 + l31;
        v8bf b = *(const v8bf*)&base[2048 + fc * 32 + ((kc ^ (fc & 3)) << 3)];
        acc[ni] = __builtin_amdgcn_mfma_f32_32x32x16_bf16(a, b, acc[ni], 0, 0, 0);
      }
    }
  };
  auto computeY = [&](int buf) {
    const __bf16* base = smem + buf * BUFS;
    v8bf a = *(const v8bf*)&base[(wr + l31) * 16 + lh * 8];
#pragma unroll
    for (int ni = 0; ni < 2; ni++) {
      v8bf b = *(const v8bf*)&base[2048 + (wc + ni * 32 + l31) * 16 + lh * 8];
      acc[ni] = __builtin_amdgcn_mfma_f32_32x32x16_bf16(a, b, acc[ni], 0, 0, 0);
    }
  };

  gload(0);
  lstore(0);
  gload(1);
  __syncthreads();
#pragma unroll
  for (int kt = 0; kt <= 16; kt++) {
    if (kt < 16) {
      if (kt < 15) lstore((kt + 1) & 1);
      else lstoreY((kt + 1) & 1);          // kt==15: stage Y-tile into buf0
      if (kt < 14) gload(kt + 2);
      else if (kt == 14) gloadY();
      compute(kt & 1);
      __syncthreads();
    } else {
      computeY(kt & 1);                    // kt==16: buf0
    }
  }
  __syncthreads();  // before reusing smem as output stage

  // ---- epilogue. C layout (32x32): col=lane&31, row=(reg&3)+8*(reg>>2)+4*lh
  if constexpr (MODE == 2) {
#pragma unroll
    for (int ni = 0; ni < 2; ni++) {
      int cl = wc + ni * 32 + l31;
#pragma unroll
      for (int reg = 0; reg < 16; reg++) {
        int rg = row0 + wr + (reg & 3) + ((reg >> 2) << 3) + (lh << 2);
        if (rg >= M) continue;
        Ofp[(size_t)rg * 256 + colblk * 128 + cl] = fmaxf(acc[ni][reg], 0.f);
      }
    }
  } else if constexpr (MODE == 0) {
#pragma unroll
    for (int ni = 0; ni < 2; ni++) {
      int cl = wc + ni * 32 + l31;
#pragma unroll
      for (int reg = 0; reg < 16; reg++) {
        int lr = wr + (reg & 3) + ((reg >> 2) << 3) + (lh << 2);
        smem[lr * 128 + cl] = (__bf16)(1.f / (1.f + expf(-acc[ni][reg])));
      }
    }
    __syncthreads();
    int row = tid >> 2, seg = (tid & 3) * 32;
    int rg = row0 + row;
    if (rg < M) {
      __bf16* dst = (colblk < 4) ? Obf : ObfR;
      int cof = (colblk & 3) * 128;
#pragma unroll
      for (int q = 0; q < 4; q++) {
        uint4 v = *(const uint4*)&smem[row * 128 + seg + q * 8];
        *(uint4*)(dst + (size_t)rg * 512 + cof + seg + q * 8) = v;
      }
    }
  } else {  // MODE 1: two 32-row passes; fp32 ht region = 32x128 = 16 KB (fits 24 KB)
    float* sF = (float*)smem;
#pragma unroll
    for (int h = 0; h < 2; h++) {
      if ((w >> 1) == h) {
#pragma unroll
        for (int ni = 0; ni < 2; ni++) {
          int cl = wc + ni * 32 + l31;
#pragma unroll
          for (int reg = 0; reg < 16; reg++) {
            int lr = (reg & 3) + ((reg >> 2) << 3) + (lh << 2);  // 0..31 local
            sF[lr * 128 + cl] = tanhf(acc[ni][reg]);
          }
        }
      }
      __syncthreads();
      int row = tid >> 3, seg = (tid & 7) * 16;
      int rg = row0 + h * 32 + row;
      if (rg < M) {
        int cg0 = colblk * 128 + seg;
#pragma unroll
        for (int q = 0; q < 2; q++) {
          v8bf z8 = *(const v8bf*)(Zbf + (size_t)rg * 512 + cg0 + q * 8);
          v8bf h8 = *(const v8bf*)(Abf + (size_t)rg * 512 + cg0 + q * 8);
          v8bf o;
#pragma unroll
          for (int j = 0; j < 8; j++) {
            float z = (float)z8[j];
            float ht = sF[row * 128 + seg + q * 8 + j];
            o[j] = (__bf16)(z * (float)h8[j] + (1.f - z) * ht);
          }
          *(v8bf*)(Obf + (size_t)rg * 512 + cg0 + q * 8) = o;
        }
      }
      if (h == 0) __syncthreads();  // protect sF before second-half writes
    }
  }
}

// acc[i,c] = sum_t probs[t] * hist[t+1][i,c];  accRelu = bf16(relu(acc))
__global__ void k_acc(const __bf16* __restrict__ hist, const float* __restrict__ probs,
                      float* __restrict__ acc, __bf16* __restrict__ accRelu, int n) {
  int idx = blockIdx.x * blockDim.x + threadIdx.x;
  if (idx >= n * 64) return;
  size_t off = (size_t)idx * 8;
  size_t S = (size_t)n * 512;
  float s[8] = {0, 0, 0, 0, 0, 0, 0, 0};
#pragma unroll
  for (int t = 0; t < TT; t++) {
    float p = probs[t];
    v8bf h = *(const v8bf*)(hist + (size_t)(t + 1) * S + off);
#pragma unroll
    for (int j = 0; j < 8; j++) s[j] = fmaf(p, (float)h[j], s[j]);
  }
  *(float4*)(acc + off) = make_float4(s[0], s[1], s[2], s[3]);
  *(float4*)(acc + off + 4) = make_float4(s[4], s[5], s[6], s[7]);
  v8bf rl;
#pragma unroll
  for (int j = 0; j < 8; j++) rl[j] = (__bf16)fmaxf(s[j], 0.f);
  *(v8bf*)(accRelu + off) = rl;
}

__global__ void k_head2(const float* __restrict__ T1, const float* __restrict__ W2,
                        const float* __restrict__ b2, float* __restrict__ out0, int M) {
  int idx = blockIdx.x * blockDim.x + threadIdx.x;
  if (idx >= M * 12) return;
  int i = idx / 12, c = idx % 12;
  const float* tr = T1 + (size_t)i * 256;
  float s = b2[c];
  for (int k = 0; k < 256; k++) s = fmaf(tr[k], W2[k * 12 + c], s);
  out0[idx] = s;
}

// ---------------- launch ----------------

extern "C" void kernel_launch(void* const* d_in, const int* in_sizes, int n_in,
                              void* d_out, int out_size, void* d_ws, size_t ws_size,
                              hipStream_t stream) {
  const float* x   = (const float*)d_in[0];
  const int*   ei  = (const int*)d_in[1];
  const float* ea  = (const float*)d_in[2];
  const float* att = (const float*)d_in[3];
  const float* Wzg = (const float*)d_in[4];  const float* bzg = (const float*)d_in[5];
  const float* Wzl = (const float*)d_in[6];  const float* bzl = (const float*)d_in[7];
  const float* Wrg = (const float*)d_in[8];  const float* brg = (const float*)d_in[9];
  const float* Wrl = (const float*)d_in[10]; const float* brl = (const float*)d_in[11];
  const float* Whg = (const float*)d_in[12]; const float* bhg = (const float*)d_in[13];
  const float* Whl = (const float*)d_in[14]; const float* bhl = (const float*)d_in[15];
  const float* W1  = (const float*)d_in[16]; const float* b1  = (const float*)d_in[17];
  const float* W2  = (const float*)d_in[18]; const float* b2  = (const float*)d_in[19];

  const int N = in_sizes[0] / NF;
  const int E = in_sizes[1] / 2;
  const int* srcI = ei;
  const int* dstI = ei + E;

  float* out0 = (float*)d_out;                   // [N,12]
  float* accO = (float*)d_out + (size_t)N * 12;  // [N,512] = H_accum (output 1)

  char* wp = (char*)d_ws;
  auto carve = [&](size_t bytes) -> void* {
    void* p = (void*)wp;
    wp += (bytes + 255) & ~(size_t)255;
    return p;
  };
  float*  deg     = (float*)carve((size_t)N * 4);
  float*  dinv    = (float*)carve((size_t)N * 4);
  float*  probs   = (float*)carve(64);
  float*  Y       = (float*)carve((size_t)N * NF * 4);
  __bf16* WzrP    = (__bf16*)carve((size_t)1024 * 512 * 2);
  __bf16* WhP     = (__bf16*)carve((size_t)512 * 512 * 2);
  __bf16* W1P     = (__bf16*)carve((size_t)256 * 512 * 2);
  float*  Wzr_eff = (float*)carve((size_t)4 * 1024 * 4);
  float*  bzr_eff = (float*)carve((size_t)1024 * 4);
  float*  Wh_eff  = (float*)carve((size_t)4 * 512 * 4);
  float*  bh_eff  = (float*)carve((size_t)512 * 4);
  __bf16* hist    = (__bf16*)carve((size_t)(TT + 1) * N * 512 * 2);  // H_0..H_12 bf16
  __bf16* Zbf     = (__bf16*)carve((size_t)N * 512 * 2);
  __bf16* Rbf     = (__bf16*)carve((size_t)N * 512 * 2);
  __bf16* accRelu = (__bf16*)carve((size_t)N * 512 * 2);
  float*  T1      = (float*)carve((size_t)N * 256 * 4);
  __bf16* Ya      = (__bf16*)carve((size_t)TT * N * 16 * 2);
  __bf16* WyZR    = (__bf16*)carve((size_t)1024 * 16 * 2);
  __bf16* WyH     = (__bf16*)carve((size_t)512 * 16 * 2);
  __bf16* Wy1     = (__bf16*)carve((size_t)256 * 16 * 2);
  int*    cnt     = (int*)carve((size_t)2 * N * 4);  // cnt[N] + fill[N] contiguous
  int*    fill    = cnt + N;
  int*    offs    = (int*)carve((size_t)(N + 1) * 4);
  int*    pscan   = (int*)carve((size_t)N * 4);
  int*    bsum    = (int*)carve(256);
  int*    bpre    = (int*)carve(256);
  int*    csrc    = (int*)carve((size_t)E * 4);
  float*  cw      = (float*)carve((size_t)E * 4);
  (void)carve(512 * 1024);  // tail pad: OOB tile reads stay inside ws
  (void)ws_size; (void)n_in; (void)out_size;

  const int TPB = 256;
  auto cdiv = [](int a, int b) { return (a + b - 1) / b; };
  const size_t S = (size_t)N * 512;

  // degree + CSR counts
  k_init<<<cdiv(N, TPB), TPB, 0, stream>>>(deg, cnt, N);
  k_edge<<<cdiv(E, TPB), TPB, 0, stream>>>(dstI, ea, deg, cnt, E);

  // hierarchical scan (+dinv) -> offs; place; gather Y = Ahat @ X
  const int nb = cdiv(N, 256);
  k_scan1<<<nb, 256, 0, stream>>>(cnt, pscan, bsum, deg, dinv, N);
  k_scan2<<<1, 128, 0, stream>>>(bsum, bpre, nb, att, probs);
  k_scan3<<<cdiv(N, TPB), TPB, 0, stream>>>(pscan, bpre, offs, N, E);
  k_place<<<cdiv(E, TPB), TPB, 0, stream>>>(srcI, dstI, ea, offs, fill, csrc, cw, E);
  k_gather<<<cdiv(N * 12, TPB), TPB, 0, stream>>>(offs, csrc, cw, dinv, x, Y, N);

  // weight prep (one packed-transpose launch; gate folds; Wy tiles)
  {
    dim3 gp(16, 8, 3);
    k_pack3<<<gp, 256, 0, stream>>>(Wzl, Wrl, Whl, W1, WzrP, WhP, W1P);
  }
  k_build_eff3<<<cdiv(3 * 5 * 512, TPB), TPB, 0, stream>>>(
      Wzg, Wzl, bzg, bzl, Wrg, Wrl, brg, brl, Whg, Whl, bhg, bhl,
      Wzr_eff, bzr_eff, Wh_eff, bh_eff);
  k_wy3<<<cdiv((1024 + 512 + 256) * 16, TPB), TPB, 0, stream>>>(
      Wzr_eff, bzr_eff, Wh_eff, bh_eff, b1, WyZR, WyH, Wy1);

  // merged Ya build + t=0 shortcut (H1 = (1-sigmoid(Yz)) * tanh(Yh))
  k_yat0<<<cdiv(N * 512 + TT * N * 16, TPB), TPB, 0, stream>>>(
      Y, Wzr_eff, bzr_eff, Wh_eff, bh_eff, Ya, hist + S, N);

  const int RB = cdiv(N, 64);          // 157 row blocks
  const int nGrp = cdiv(RB, 8);        // 20 groups
  for (int t = 1; t < TT; t++) {
    const __bf16* Hbt = hist + (size_t)t * S;
    __bf16* Hbn = hist + (size_t)(t + 1) * S;
    const __bf16* Yat = Ya + (size_t)t * N * 16;
    k_mm<0><<<64 * nGrp, 256, 0, stream>>>(Hbt, WzrP, nullptr, nullptr, Yat, WyZR,
                                           nullptr, Zbf, Rbf, N, RB);
    k_mm<1><<<32 * nGrp, 256, 0, stream>>>(Hbt, WhP, Rbf, Zbf, Yat, WyH,
                                           nullptr, Hbn, nullptr, N, RB);
  }

  // H_accum = sum_t p_t H_{t+1}; head
  k_acc<<<cdiv(N * 64, TPB), TPB, 0, stream>>>(hist, probs, accO, accRelu, N);
  k_mm<2><<<16 * nGrp, 256, 0, stream>>>(accRelu, W1P, nullptr, nullptr, Ya, Wy1,
                                         T1, nullptr, nullptr, N, RB);
  k_head2<<<cdiv(N * 12, TPB), TPB, 0, stream>>>(T1, W2, b2, out0, N);
}